// Round 2
// baseline (1019.371 us; speedup 1.0000x reference)
//
#include <hip/hip_runtime.h>
#include <math.h>

// Kalman forward LL: Woodbury reduction to 16-dim + steady-state Riccati +
// chunked parallel scan over time for the mean recursion.
// Scratch is a __device__ global (no dependence on harness ws_size).

#define T_TOT 8192
#define NTR   32
#define VD    64
#define NCHUNK 128
#define CHLEN  64
#define NE     64     // exact stored covariance steps (== CHLEN)
#define MAXIT  512

// ---- workspace layout (in floats; doubles occupy wf[0..7]) ----
#define OFF_FS   8                        // fs[0]=c0, fs[1]=c
#define OFF_S    16
#define OFF_P0   (OFF_S+256)
#define OFF_PSS  (OFF_P0+256)
#define OFF_M0   (OFF_PSS+256)
#define OFF_M64  (OFF_M0+256)
#define OFF_PST  (OFF_M64+256)            // NE*256
#define OFF_FQ   (OFF_PST+NE*256)         // 32
#define OFF_VC   (OFF_FQ+32)              // NCHUNK*512
#define OFF_EN   (OFF_VC+NCHUNK*512)      // NCHUNK*512
#define OFF_QS   (OFF_EN+NCHUNK*512)      // NCHUNK*32
#define OFF_Q    (OFF_QS+NCHUNK*32)       // T_TOT*512
#define OFF_XX   (OFF_Q+T_TOT*512)        // T_TOT*32
#define WS_FLOATS (OFF_XX + T_TOT*32)

__device__ float g_wf[WS_FLOATS];

// ---- lane swizzle helpers (16-lane groups) ----
#define SWZ(x, imm) __int_as_float(__builtin_amdgcn_ds_swizzle(__float_as_int(x), (imm)))

// out_j = sum_k row[k] * v_k  (row = M[j][:] held per-lane; v distributed lane j = comp j)
#define MV16(row, vv, out) do { \
  float b0_=SWZ(vv,0x010), b1_=SWZ(vv,0x030), b2_=SWZ(vv,0x050), b3_=SWZ(vv,0x070); \
  float b4_=SWZ(vv,0x090), b5_=SWZ(vv,0x0B0), b6_=SWZ(vv,0x0D0), b7_=SWZ(vv,0x0F0); \
  float b8_=SWZ(vv,0x110), b9_=SWZ(vv,0x130), b10_=SWZ(vv,0x150), b11_=SWZ(vv,0x170); \
  float b12_=SWZ(vv,0x190), b13_=SWZ(vv,0x1B0), b14_=SWZ(vv,0x1D0), b15_=SWZ(vv,0x1F0); \
  float s0_=fmaf((row)[0],b0_,fmaf((row)[1],b1_,fmaf((row)[2],b2_,(row)[3]*b3_))); \
  float s1_=fmaf((row)[4],b4_,fmaf((row)[5],b5_,fmaf((row)[6],b6_,(row)[7]*b7_))); \
  float s2_=fmaf((row)[8],b8_,fmaf((row)[9],b9_,fmaf((row)[10],b10_,(row)[11]*b11_))); \
  float s3_=fmaf((row)[12],b12_,fmaf((row)[13],b13_,fmaf((row)[14],b14_,(row)[15]*b15_))); \
  (out)=(s0_+s1_)+(s2_+s3_); \
} while(0)

// full 16-lane-group sum (result in all 16 lanes)
#define RED16(x) do { x+=SWZ(x,0x041F); x+=SWZ(x,0x081F); x+=SWZ(x,0x101F); x+=SWZ(x,0x201F); } while(0)

// =====================================================================
// K0: q[t][n][:] = W^T x_{t,n},  xx[t][n] = ||x_{t,n}||^2
// =====================================================================
__global__ __launch_bounds__(256) void k_q(const float* __restrict__ v,
                                           const float* __restrict__ W)
{
  __shared__ float Wl[VD][16];
  const int tid = threadIdx.x;
  for (int e = tid; e < VD*16; e += 256) Wl[e>>4][e&15] = W[e];
  __syncthreads();
  const int n = blockIdx.y;
  const int t = blockIdx.x*256 + tid;
  const float* vp = v + (size_t)n*VD*T_TOT + t;
  float acc[16];
  #pragma unroll
  for (int k = 0; k < 16; ++k) acc[k] = 0.f;
  float s2 = 0.f;
  for (int i2 = 0; i2 < VD; ++i2) {
    float x = vp[(size_t)i2*T_TOT];
    s2 = fmaf(x, x, s2);
    const float4* wr = (const float4*)&Wl[i2][0];
    float4 w0 = wr[0], w1 = wr[1], w2 = wr[2], w3 = wr[3];
    acc[0]=fmaf(x,w0.x,acc[0]);  acc[1]=fmaf(x,w0.y,acc[1]);
    acc[2]=fmaf(x,w0.z,acc[2]);  acc[3]=fmaf(x,w0.w,acc[3]);
    acc[4]=fmaf(x,w1.x,acc[4]);  acc[5]=fmaf(x,w1.y,acc[5]);
    acc[6]=fmaf(x,w1.z,acc[6]);  acc[7]=fmaf(x,w1.w,acc[7]);
    acc[8]=fmaf(x,w2.x,acc[8]);  acc[9]=fmaf(x,w2.y,acc[9]);
    acc[10]=fmaf(x,w2.z,acc[10]); acc[11]=fmaf(x,w2.w,acc[11]);
    acc[12]=fmaf(x,w3.x,acc[12]); acc[13]=fmaf(x,w3.y,acc[13]);
    acc[14]=fmaf(x,w3.z,acc[14]); acc[15]=fmaf(x,w3.w,acc[15]);
  }
  float4* qo = (float4*)(g_wf + OFF_Q + ((size_t)t*32 + n)*16);
  qo[0] = make_float4(acc[0],acc[1],acc[2],acc[3]);
  qo[1] = make_float4(acc[4],acc[5],acc[6],acc[7]);
  qo[2] = make_float4(acc[8],acc[9],acc[10],acc[11]);
  qo[3] = make_float4(acc[12],acc[13],acc[14],acc[15]);
  g_wf[OFF_XX + (size_t)t*32 + n] = s2;
}

// =====================================================================
// K1 (single wave): Riccati covariance recursion, 16x16 algebra only.
// =====================================================================
__device__ __forceinline__ void mm16(float (*C)[16], float (*Aa)[16], float (*Bb)[16])
{
  const int tid = threadIdx.x; const int i = tid>>2; const int c4 = (tid&3)<<2;
  __syncthreads();
  float a0=0.f,a1=0.f,a2=0.f,a3=0.f;
  #pragma unroll
  for (int k = 0; k < 16; ++k) {
    float a = Aa[i][k];
    a0=fmaf(a,Bb[k][c4+0],a0); a1=fmaf(a,Bb[k][c4+1],a1);
    a2=fmaf(a,Bb[k][c4+2],a2); a3=fmaf(a,Bb[k][c4+3],a3);
  }
  __syncthreads();
  C[i][c4+0]=a0; C[i][c4+1]=a1; C[i][c4+2]=a2; C[i][c4+3]=a3;
  __syncthreads();
}

__device__ __forceinline__ void mm16_bt(float (*C)[16], float (*Aa)[16], float (*Bb)[16])
{
  const int tid = threadIdx.x; const int i = tid>>2; const int c4 = (tid&3)<<2;
  __syncthreads();
  float a0=0.f,a1=0.f,a2=0.f,a3=0.f;
  #pragma unroll
  for (int k = 0; k < 16; ++k) {
    float a = Aa[i][k];
    a0=fmaf(a,Bb[c4+0][k],a0); a1=fmaf(a,Bb[c4+1][k],a1);
    a2=fmaf(a,Bb[c4+2][k],a2); a3=fmaf(a,Bb[c4+3][k],a3);
  }
  __syncthreads();
  C[i][c4+0]=a0; C[i][c4+1]=a1; C[i][c4+2]=a2; C[i][c4+3]=a3;
  __syncthreads();
}

// Gauss-Jordan inverse of SPD 16x16 (in LDS), returns log|det| (same in all lanes).
__device__ float inv16_gj(float (*Mw)[16], float (*Ow)[16])
{
  const int tid = threadIdx.x; const int i = tid>>2; const int c4 = (tid&3)<<2;
  #pragma unroll
  for (int cc = 0; cc < 4; ++cc) Ow[i][c4+cc] = (i == (c4+cc)) ? 1.f : 0.f;
  __syncthreads();
  float ld = 0.f;
  for (int k = 0; k < 16; ++k) {
    float p = Mw[k][k];
    ld += logf(p);
    float r = 1.f/p;
    float rk0=Mw[k][c4+0], rk1=Mw[k][c4+1], rk2=Mw[k][c4+2], rk3=Mw[k][c4+3];
    float ok0=Ow[k][c4+0], ok1=Ow[k][c4+1], ok2=Ow[k][c4+2], ok3=Ow[k][c4+3];
    float f = Mw[i][k]*r;
    __syncthreads();
    if (i == k) {
      Mw[k][c4+0]=rk0*r; Mw[k][c4+1]=rk1*r; Mw[k][c4+2]=rk2*r; Mw[k][c4+3]=rk3*r;
      Ow[k][c4+0]=ok0*r; Ow[k][c4+1]=ok1*r; Ow[k][c4+2]=ok2*r; Ow[k][c4+3]=ok3*r;
    } else {
      Mw[i][c4+0]-=f*rk0; Mw[i][c4+1]-=f*rk1; Mw[i][c4+2]-=f*rk2; Mw[i][c4+3]-=f*rk3;
      Ow[i][c4+0]-=f*ok0; Ow[i][c4+1]-=f*ok1; Ow[i][c4+2]-=f*ok2; Ow[i][c4+3]-=f*ok3;
    }
    __syncthreads();
  }
  return ld;
}

__global__ __launch_bounds__(64) void k_cov(const float* __restrict__ A,
                                            const float* __restrict__ B,
                                            const float* __restrict__ W,
                                            const float* __restrict__ S0h,
                                            const float* __restrict__ lsv)
{
  __shared__ float Wl[VD][16];
  __shared__ float S[16][16], Al[16][16], Q[16][16], M1[16][16], M2[16][16];
  __shared__ float Sf[16][16], T1[16][16], X[16][16], P[16][16];
  __shared__ float AP[16][16], Fm[16][16], CM[16][16], TM[16][16];
  const int tid = threadIdx.x; const int i = tid>>2; const int c4 = (tid&3)<<2;
  float* __restrict__ wf = g_wf;

  for (int e = tid; e < VD*16; e += 64) Wl[e>>4][e&15] = W[e];
  for (int e = tid; e < 256; e += 64) Al[e>>4][e&15] = A[e];
  __syncthreads();
  // S = W^T W ; Q = tril(B)tril(B)^T + 1e-6 I ; M1 = Sigma0
  for (int e = tid; e < 256; e += 64) {
    int a = e>>4, b = e&15; float s = 0.f;
    for (int r = 0; r < VD; ++r) s = fmaf(Wl[r][a], Wl[r][b], s);
    S[a][b] = s;
  }
  for (int e = tid; e < 256; e += 64) {
    int a = e>>4, b = e&15; float s = (a==b)?1e-6f:0.f;
    int m = a < b ? a : b;
    for (int r = 0; r <= m; ++r) s = fmaf(B[a*16+r], B[b*16+r], s);
    Q[a][b] = s;
  }
  for (int e = tid; e < 256; e += 64) {
    int a = e>>4, b = e&15; float s = (a==b)?1e-6f:0.f;
    int m = a < b ? a : b;
    for (int r = 0; r <= m; ++r) s = fmaf(S0h[a*16+r], S0h[b*16+r], s);
    M1[a][b] = s;
  }
  __syncthreads();
  float ev = expf(lsv[0]); float var = ev*ev;
  float c0 = var + 1e-6f, c = var + 2e-6f;
  float invc0 = 1.f/c0, invc = 1.f/c;

  // P0' = (Sigma0^{-1} + S/c0)^{-1}
  float ldS0 = inv16_gj(M1, X);
  for (int e = tid; e < 256; e += 64) { int a=e>>4,b=e&15; M2[a][b] = X[a][b] + S[a][b]*invc0; }
  __syncthreads();
  float ldE0 = inv16_gj(M2, P);
  float ldet_first = 0.5f*(64.f*logf(c0) + ldS0 + ldE0);
  for (int e = tid; e < 256; e += 64) { wf[OFF_P0+e] = P[e>>4][e&15]; wf[OFF_S+e] = S[e>>4][e&15]; }
  for (int e = tid; e < 256; e += 64) { int a=e>>4,b=e&15; Sf[a][b] = P[a][b]; CM[a][b] = (a==b)?1.f:0.f; }
  __syncthreads();

  double dacc = 0.0; float ld_t = 0.f;
  #pragma unroll 1
  for (int t = 1; t <= MAXIT; ++t) {
    mm16(T1, Al, Sf);          // T1 = A*Sf
    mm16_bt(M1, T1, Al);       // M1 = T1*A^T
    { // symmetrize + add Q
      float s0_ = 0.5f*(M1[i][c4+0] + M1[c4+0][i]) + Q[i][c4+0];
      float s1_ = 0.5f*(M1[i][c4+1] + M1[c4+1][i]) + Q[i][c4+1];
      float s2_ = 0.5f*(M1[i][c4+2] + M1[c4+2][i]) + Q[i][c4+2];
      float s3_ = 0.5f*(M1[i][c4+3] + M1[c4+3][i]) + Q[i][c4+3];
      __syncthreads();
      M1[i][c4+0]=s0_; M1[i][c4+1]=s1_; M1[i][c4+2]=s2_; M1[i][c4+3]=s3_;
      __syncthreads();
    }
    float ldSd = inv16_gj(M1, X);          // X = Sd^{-1}
    for (int e = tid; e < 256; e += 64) { int a=e>>4,b=e&15; M2[a][b] = X[a][b] + S[a][b]*invc; }
    __syncthreads();
    float ldE = inv16_gj(M2, P);           // P = Sf_t
    ld_t = 0.5f*(64.f*logf(c) + ldSd + ldE);
    if (t <= NE) {
      dacc += (double)ld_t;
      for (int e = tid; e < 256; e += 64) wf[OFF_PST + (t-1)*256 + e] = P[e>>4][e&15];
      mm16(AP, Al, P);
      mm16(Fm, AP, S);
      for (int e = tid; e < 256; e += 64) { int a=e>>4,b=e&15; Fm[a][b] = Al[a][b] - Fm[a][b]*invc; }
      __syncthreads();
      mm16(TM, Fm, CM);
      for (int e = tid; e < 256; e += 64) CM[e>>4][e&15] = TM[e>>4][e&15];
      __syncthreads();
    }
    // convergence check + copy P -> Sf
    float d0_=fabsf(P[i][c4+0]-Sf[i][c4+0]), d1_=fabsf(P[i][c4+1]-Sf[i][c4+1]);
    float d2_=fabsf(P[i][c4+2]-Sf[i][c4+2]), d3_=fabsf(P[i][c4+3]-Sf[i][c4+3]);
    float dmax = fmaxf(fmaxf(d0_,d1_), fmaxf(d2_,d3_));
    float pmax = fmaxf(fmaxf(fabsf(P[i][c4+0]),fabsf(P[i][c4+1])),
                       fmaxf(fabsf(P[i][c4+2]),fabsf(P[i][c4+3])));
    #pragma unroll
    for (int m2 = 1; m2 < 64; m2 <<= 1) {
      dmax = fmaxf(dmax, __shfl_xor(dmax, m2));
      pmax = fmaxf(pmax, __shfl_xor(pmax, m2));
    }
    Sf[i][c4+0]=P[i][c4+0]; Sf[i][c4+1]=P[i][c4+1];
    Sf[i][c4+2]=P[i][c4+2]; Sf[i][c4+3]=P[i][c4+3];
    __syncthreads();
    if (t >= NE+4 && dmax <= 1e-6f*pmax) break;
  }

  double ldet_total = dacc + (double)(T_TOT-1-NE)*(double)ld_t;
  for (int e = tid; e < 256; e += 64) wf[OFF_PSS+e] = Sf[e>>4][e&15];
  // F_ss = A - (A P_ss)(S/c) ; M64 = F_ss^64
  mm16(AP, Al, Sf);
  mm16(Fm, AP, S);
  for (int e = tid; e < 256; e += 64) { int a=e>>4,b=e&15; Fm[a][b] = Al[a][b] - Fm[a][b]*invc; }
  __syncthreads();
  mm16(TM, Fm, Fm);   // ^2
  mm16(Fm, TM, TM);   // ^4
  mm16(TM, Fm, Fm);   // ^8
  mm16(Fm, TM, TM);   // ^16
  mm16(TM, Fm, Fm);   // ^32
  mm16(Fm, TM, TM);   // ^64
  for (int e = tid; e < 256; e += 64) { wf[OFF_M64+e] = Fm[e>>4][e&15]; wf[OFF_M0+e] = CM[e>>4][e&15]; }
  if (tid == 0) {
    double* d = (double*)wf;
    d[0] = (double)ldet_first;
    d[1] = ldet_total;
    wf[OFF_FS+0] = c0; wf[OFF_FS+1] = c;
  }
}

// =====================================================================
// Pass A: chunk-local affine offsets (recursion from zero state).
// 512 threads = 32 trials x 16 lanes; one block per chunk.
// =====================================================================
__global__ __launch_bounds__(512) void k_passA(const float* __restrict__ A)
{
  const int tid = threadIdx.x; const int j = tid & 15; const int chunk = blockIdx.x;
  float* __restrict__ wf = g_wf;
  float Ar[16], Sr[16], Pr[16];
  #pragma unroll
  for (int k = 0; k < 16; ++k) {
    Ar[k] = A[j*16+k];
    Sr[k] = wf[OFF_S  + j*16 + k];
    Pr[k] = wf[OFF_PSS+ j*16 + k];
  }
  const float c = wf[OFF_FS+1]; const float invc = 1.f/c;
  const int t0 = 1 + CHLEN*chunk;
  const int ns = (CHLEN < (T_TOT-1) - t0 + 1) ? CHLEN : ((T_TOT-1) - t0 + 1);
  const float* qp = wf + OFF_Q + (size_t)t0*512 + tid;
  float mud = 0.f;
  if (chunk == 0) {
    const float* pst = wf + OFF_PST + j*16;
    #pragma unroll 1
    for (int s = 0; s < CHLEN; ++s) {
      float Pt[16];
      #pragma unroll
      for (int k = 0; k < 16; ++k) Pt[k] = pst[s*256 + k];
      float qj = qp[0]; qp += 512;
      float h; MV16(Sr, mud, h);
      float u = qj - h;
      float w; MV16(Pt, u, w);
      float tmp = fmaf(w, invc, mud);
      MV16(Ar, tmp, mud);
    }
  } else {
    #pragma unroll 1
    for (int s = 0; s < ns; ++s) {
      float qj = qp[0]; qp += 512;
      float h; MV16(Sr, mud, h);
      float u = qj - h;
      float w; MV16(Pr, u, w);
      float tmp = fmaf(w, invc, mud);
      MV16(Ar, tmp, mud);
    }
  }
  wf[OFF_VC + chunk*512 + tid] = mud;
}

// =====================================================================
// Pass B: t=0 term + serial scan over 128 chunk maps (one block).
// =====================================================================
__global__ __launch_bounds__(512) void k_passB(const float* __restrict__ A,
                                               const float* __restrict__ mu0)
{
  const int tid = threadIdx.x; const int j = tid & 15; const int n = tid >> 4;
  float* __restrict__ wf = g_wf;
  float Ar[16], Sr[16], P0r[16], M0r[16], M64r[16];
  #pragma unroll
  for (int k = 0; k < 16; ++k) {
    Ar[k]   = A[j*16+k];
    Sr[k]   = wf[OFF_S  + j*16 + k];
    P0r[k]  = wf[OFF_P0 + j*16 + k];
    M0r[k]  = wf[OFF_M0 + j*16 + k];
    M64r[k] = wf[OFF_M64+ j*16 + k];
  }
  const float c0 = wf[OFF_FS+0]; const float invc0 = 1.f/c0;
  float mu0j = mu0[j];
  float q0  = wf[OFF_Q + tid];       // t = 0
  float xx0 = wf[OFF_XX + n];
  float h0; MV16(Sr, mu0j, h0);
  float u0 = q0 - h0;
  float w0; MV16(P0r, u0, w0);
  float loc = fmaf(-2.f*q0, mu0j, fmaf(mu0j, h0, -(u0*w0*invc0)));
  RED16(loc);
  float fq = (xx0 + loc)*invc0;
  if (j == 0) wf[OFF_FQ + n] = fq;
  float muf = fmaf(w0, invc0, mu0j);
  float en; MV16(Ar, muf, en);       // entry_0 = mud_1 = A*muf0
  #pragma unroll 1
  for (int ii = 0; ii < NCHUNK; ++ii) {
    wf[OFF_EN + ii*512 + tid] = en;
    float vv = wf[OFF_VC + ii*512 + tid];
    float nx;
    if (ii == 0) { MV16(M0r, en, nx); } else { MV16(M64r, en, nx); }
    en = nx + vv;
  }
}

// =====================================================================
// Pass C: replay chunks from true entries, accumulate LL quadratics.
// =====================================================================
__global__ __launch_bounds__(512) void k_passC(const float* __restrict__ A)
{
  const int tid = threadIdx.x; const int j = tid & 15; const int n = tid >> 4;
  const int chunk = blockIdx.x;
  float* __restrict__ wf = g_wf;
  float Ar[16], Sr[16], Pr[16];
  #pragma unroll
  for (int k = 0; k < 16; ++k) {
    Ar[k] = A[j*16+k];
    Sr[k] = wf[OFF_S  + j*16 + k];
    Pr[k] = wf[OFF_PSS+ j*16 + k];
  }
  const float c = wf[OFF_FS+1]; const float invc = 1.f/c;
  const int t0 = 1 + CHLEN*chunk;
  const int ns = (CHLEN < (T_TOT-1) - t0 + 1) ? CHLEN : ((T_TOT-1) - t0 + 1);
  const float* qp  = wf + OFF_Q  + (size_t)t0*512 + tid;
  const float* xxp = wf + OFF_XX + (size_t)t0*32 + n;
  float mud = wf[OFF_EN + chunk*512 + tid];
  float qacc = 0.f;

#define QSTEP(PROW) do { \
    float qj = qp[0]; qp += 512; \
    float xxv = xxp[0]; xxp += 32; \
    float h; MV16(Sr, mud, h); \
    float u = qj - h; \
    float w; MV16(PROW, u, w); \
    float loc = fmaf(-2.f*qj, mud, fmaf(mud, h, -(u*w*invc))); \
    RED16(loc); \
    qacc = fmaf(xxv + loc, invc, qacc); \
    float tmp = fmaf(w, invc, mud); \
    MV16(Ar, tmp, mud); \
  } while(0)

  if (chunk == 0) {
    const float* pst = wf + OFF_PST + j*16;
    #pragma unroll 1
    for (int s = 0; s < CHLEN; ++s) {
      float Pt[16];
      #pragma unroll
      for (int k = 0; k < 16; ++k) Pt[k] = pst[s*256 + k];
      QSTEP(Pt);
    }
  } else {
    #pragma unroll 1
    for (int s = 0; s < ns; ++s) QSTEP(Pr);
  }
#undef QSTEP
  if (j == 0) wf[OFF_QS + chunk*32 + n] = qacc;
}

// =====================================================================
// Final assembly.
// =====================================================================
__global__ __launch_bounds__(64) void k_final(float* __restrict__ out)
{
  const int n = threadIdx.x;
  if (n >= NTR) return;
  const float* wf = g_wf;
  const double* dsc = (const double*)wf;
  double acc = (double)wf[OFF_FQ + n];
  for (int i = 0; i < NCHUNK; ++i) acc += (double)wf[OFF_QS + i*32 + n];
  const double LOG2PI = 1.8378770664093453;
  double ll = -32.0*LOG2PI*(double)T_TOT - dsc[0] - dsc[1] - 0.5*acc;
  out[n] = (float)ll;
}

extern "C" void kernel_launch(void* const* d_in, const int* in_sizes, int n_in,
                              void* d_out, int out_size, void* d_ws, size_t ws_size,
                              hipStream_t stream)
{
  (void)in_sizes; (void)n_in; (void)out_size; (void)d_ws; (void)ws_size;
  const float* v   = (const float*)d_in[0];
  const float* A   = (const float*)d_in[1];
  const float* B   = (const float*)d_in[2];
  const float* W   = (const float*)d_in[3];
  const float* mu0 = (const float*)d_in[4];
  const float* S0h = (const float*)d_in[5];
  const float* lsv = (const float*)d_in[6];
  float* out = (float*)d_out;

  dim3 g0(T_TOT/256, NTR);
  k_q    <<<g0,     256, 0, stream>>>(v, W);
  k_cov  <<<1,      64,  0, stream>>>(A, B, W, S0h, lsv);
  k_passA<<<NCHUNK, 512, 0, stream>>>(A);
  k_passB<<<1,      512, 0, stream>>>(A, mu0);
  k_passC<<<NCHUNK, 512, 0, stream>>>(A);
  k_final<<<1,      64,  0, stream>>>(out);
}

// Round 3
// 589.628 us; speedup vs baseline: 1.7288x; 1.7288x over previous
//
#include <hip/hip_runtime.h>
#include <math.h>

// Kalman forward LL: Woodbury reduction to 16-dim + steady-state Riccati
// (G-trick: G = I + Sd*S/c, P = G^-1 Sd, F = A G^-1, logdet via det lemma)
// + chunked parallel scan over time for the mean recursion.

#define T_TOT 8192
#define NTR   32
#define VD    64
#define NCHUNK 128
#define CHLEN  64
#define NI     64     // exact Riccati iterations (then steady state)

// ---- workspace layout (floats; doubles occupy wf[0..7]) ----
#define OFF_FS   8                        // c0, c, invc, invc0
#define OFF_S    16
#define OFF_P0   (OFF_S+256)
#define OFF_PSS  (OFF_P0+256)
#define OFF_F    (OFF_PSS+256)
#define OFF_M64  (OFF_F+256)
#define OFF_KQ   (OFF_M64+256)
#define OFF_FQ   (OFF_KQ+256)             // 32
#define OFF_VC   (OFF_FQ+32)              // NCHUNK*512
#define OFF_EN   (OFF_VC+NCHUNK*512)      // NCHUNK*512
#define OFF_QS   (OFF_EN+NCHUNK*512)      // NCHUNK*32
#define OFF_Q    (OFF_QS+NCHUNK*32)       // T_TOT*512
#define OFF_XX   (OFF_Q+T_TOT*512)        // T_TOT*32
#define WS_FLOATS (OFF_XX + T_TOT*32)

__device__ float g_wf[WS_FLOATS];

#define WB() __builtin_amdgcn_wave_barrier()

// ---- lane swizzle helpers (16-lane groups) ----
#define SWZ(x, imm) __int_as_float(__builtin_amdgcn_ds_swizzle(__float_as_int(x), (imm)))

// out_j = sum_k row[k] * v_k  (row = M[j][:] per-lane; v distributed lane j = comp j)
#define MV16(row, vv, out) do { \
  float b0_=SWZ(vv,0x010), b1_=SWZ(vv,0x030), b2_=SWZ(vv,0x050), b3_=SWZ(vv,0x070); \
  float b4_=SWZ(vv,0x090), b5_=SWZ(vv,0x0B0), b6_=SWZ(vv,0x0D0), b7_=SWZ(vv,0x0F0); \
  float b8_=SWZ(vv,0x110), b9_=SWZ(vv,0x130), b10_=SWZ(vv,0x150), b11_=SWZ(vv,0x170); \
  float b12_=SWZ(vv,0x190), b13_=SWZ(vv,0x1B0), b14_=SWZ(vv,0x1D0), b15_=SWZ(vv,0x1F0); \
  float s0_=fmaf((row)[0],b0_,fmaf((row)[1],b1_,fmaf((row)[2],b2_,(row)[3]*b3_))); \
  float s1_=fmaf((row)[4],b4_,fmaf((row)[5],b5_,fmaf((row)[6],b6_,(row)[7]*b7_))); \
  float s2_=fmaf((row)[8],b8_,fmaf((row)[9],b9_,fmaf((row)[10],b10_,(row)[11]*b11_))); \
  float s3_=fmaf((row)[12],b12_,fmaf((row)[13],b13_,fmaf((row)[14],b14_,(row)[15]*b15_))); \
  (out)=(s0_+s1_)+(s2_+s3_); \
} while(0)

// full 16-lane-group sum (result in all 16 lanes)
#define RED16(x) do { x+=SWZ(x,0x041F); x+=SWZ(x,0x081F); x+=SWZ(x,0x101F); x+=SWZ(x,0x201F); } while(0)

// =====================================================================
// single-wave 16x16 helpers (wave-synchronous: no s_barrier)
// =====================================================================
__device__ __forceinline__ void mm16w(float (*C)[16], float (*Aa)[16], float (*Bb)[16])
{
  const int tid = threadIdx.x; const int i = tid>>2; const int c4 = (tid&3)<<2;
  WB();
  float a0=0.f,a1=0.f,a2=0.f,a3=0.f;
  #pragma unroll
  for (int k = 0; k < 16; ++k) {
    float a = Aa[i][k];
    a0=fmaf(a,Bb[k][c4+0],a0); a1=fmaf(a,Bb[k][c4+1],a1);
    a2=fmaf(a,Bb[k][c4+2],a2); a3=fmaf(a,Bb[k][c4+3],a3);
  }
  WB();
  C[i][c4+0]=a0; C[i][c4+1]=a1; C[i][c4+2]=a2; C[i][c4+3]=a3;
  WB();
}

__device__ __forceinline__ void mm16bt(float (*C)[16], float (*Aa)[16], float (*Bb)[16])
{
  const int tid = threadIdx.x; const int i = tid>>2; const int c4 = (tid&3)<<2;
  WB();
  float a0=0.f,a1=0.f,a2=0.f,a3=0.f;
  #pragma unroll
  for (int k = 0; k < 16; ++k) {
    float a = Aa[i][k];
    a0=fmaf(a,Bb[c4+0][k],a0); a1=fmaf(a,Bb[c4+1][k],a1);
    a2=fmaf(a,Bb[c4+2][k],a2); a3=fmaf(a,Bb[c4+3][k],a3);
  }
  WB();
  C[i][c4+0]=a0; C[i][c4+1]=a1; C[i][c4+2]=a2; C[i][c4+3]=a3;
  WB();
}

// Gauss-Jordan inverse of 16x16 (in LDS), returns log|det| (all lanes).
__device__ float inv16w(float (*Mw)[16], float (*Ow)[16])
{
  const int tid = threadIdx.x; const int i = tid>>2; const int c4 = (tid&3)<<2;
  #pragma unroll
  for (int cc = 0; cc < 4; ++cc) Ow[i][c4+cc] = (i == (c4+cc)) ? 1.f : 0.f;
  WB();
  float ld = 0.f;
  #pragma unroll 1
  for (int k = 0; k < 16; ++k) {
    float p = Mw[k][k];
    ld += logf(fabsf(p));
    float r = 1.f/p;
    float rk0=Mw[k][c4+0], rk1=Mw[k][c4+1], rk2=Mw[k][c4+2], rk3=Mw[k][c4+3];
    float ok0=Ow[k][c4+0], ok1=Ow[k][c4+1], ok2=Ow[k][c4+2], ok3=Ow[k][c4+3];
    float f = Mw[i][k]*r;
    WB();
    if (i == k) {
      Mw[k][c4+0]=rk0*r; Mw[k][c4+1]=rk1*r; Mw[k][c4+2]=rk2*r; Mw[k][c4+3]=rk3*r;
      Ow[k][c4+0]=ok0*r; Ow[k][c4+1]=ok1*r; Ow[k][c4+2]=ok2*r; Ow[k][c4+3]=ok3*r;
    } else {
      Mw[i][c4+0]-=f*rk0; Mw[i][c4+1]-=f*rk1; Mw[i][c4+2]-=f*rk2; Mw[i][c4+3]-=f*rk3;
      Ow[i][c4+0]-=f*ok0; Ow[i][c4+1]-=f*ok1; Ow[i][c4+2]-=f*ok2; Ow[i][c4+3]-=f*ok3;
    }
    WB();
  }
  return ld;
}

// =====================================================================
// Fused front: block 0 = Riccati (64 threads, 1 wave); blocks>=1 = q/xx.
// =====================================================================
__global__ __launch_bounds__(256) void k_front(const float* __restrict__ v,
                                               const float* __restrict__ A,
                                               const float* __restrict__ B,
                                               const float* __restrict__ W,
                                               const float* __restrict__ S0h,
                                               const float* __restrict__ lsv)
{
  const int tid = threadIdx.x;
  float* __restrict__ wf = g_wf;

  if (blockIdx.x != 0) {
    // ---------------- q-pass ----------------
    __shared__ float Wl[VD][16];
    for (int e = tid; e < VD*16; e += 256) Wl[e>>4][e&15] = W[e];
    __syncthreads();
    const int bid = blockIdx.x - 1;
    const int n = bid >> 5;
    const int t = (bid & 31)*256 + tid;
    const float* vp = v + (size_t)n*VD*T_TOT + t;
    float acc[16];
    #pragma unroll
    for (int k = 0; k < 16; ++k) acc[k] = 0.f;
    float s2 = 0.f;
    for (int i2 = 0; i2 < VD; ++i2) {
      float x = vp[(size_t)i2*T_TOT];
      s2 = fmaf(x, x, s2);
      const float4* wr = (const float4*)&Wl[i2][0];
      float4 w0 = wr[0], w1 = wr[1], w2 = wr[2], w3 = wr[3];
      acc[0]=fmaf(x,w0.x,acc[0]);  acc[1]=fmaf(x,w0.y,acc[1]);
      acc[2]=fmaf(x,w0.z,acc[2]);  acc[3]=fmaf(x,w0.w,acc[3]);
      acc[4]=fmaf(x,w1.x,acc[4]);  acc[5]=fmaf(x,w1.y,acc[5]);
      acc[6]=fmaf(x,w1.z,acc[6]);  acc[7]=fmaf(x,w1.w,acc[7]);
      acc[8]=fmaf(x,w2.x,acc[8]);  acc[9]=fmaf(x,w2.y,acc[9]);
      acc[10]=fmaf(x,w2.z,acc[10]); acc[11]=fmaf(x,w2.w,acc[11]);
      acc[12]=fmaf(x,w3.x,acc[12]); acc[13]=fmaf(x,w3.y,acc[13]);
      acc[14]=fmaf(x,w3.z,acc[14]); acc[15]=fmaf(x,w3.w,acc[15]);
    }
    float4* qo = (float4*)(wf + OFF_Q + ((size_t)t*32 + n)*16);
    qo[0] = make_float4(acc[0],acc[1],acc[2],acc[3]);
    qo[1] = make_float4(acc[4],acc[5],acc[6],acc[7]);
    qo[2] = make_float4(acc[8],acc[9],acc[10],acc[11]);
    qo[3] = make_float4(acc[12],acc[13],acc[14],acc[15]);
    wf[OFF_XX + (size_t)t*32 + n] = s2;
    return;
  }

  // ---------------- Riccati (single wave) ----------------
  if (tid >= 64) return;
  __shared__ float Wl[VD][16];
  __shared__ float Al[16][16], Sm[16][16], Qm[16][16], Scl[16][16];
  __shared__ float B1[16][16], B2[16][16], B3[16][16], B4[16][16], B5[16][16], B6[16][16];

  for (int e = tid; e < VD*16; e += 64) Wl[e>>4][e&15] = W[e];
  for (int e = tid; e < 256; e += 64) Al[e>>4][e&15] = A[e];
  WB();
  for (int e = tid; e < 256; e += 64) {
    int a = e>>4, b = e&15; float s = 0.f;
    for (int r = 0; r < VD; ++r) s = fmaf(Wl[r][a], Wl[r][b], s);
    Sm[a][b] = s;
  }
  for (int e = tid; e < 256; e += 64) {
    int a = e>>4, b = e&15; float s = (a==b)?1e-6f:0.f;
    int m = a < b ? a : b;
    for (int r = 0; r <= m; ++r) s = fmaf(B[a*16+r], B[b*16+r], s);
    Qm[a][b] = s;
  }
  for (int e = tid; e < 256; e += 64) {         // B1 = Sigma0
    int a = e>>4, b = e&15; float s = (a==b)?1e-6f:0.f;
    int m = a < b ? a : b;
    for (int r = 0; r <= m; ++r) s = fmaf(S0h[a*16+r], S0h[b*16+r], s);
    B1[a][b] = s;
  }
  WB();
  float ev = expf(lsv[0]); float var = ev*ev;
  float c0 = var + 1e-6f, c = var + 2e-6f;
  float invc0 = 1.f/c0, invc = 1.f/c;

  // ---- t=0: G0 = I + Sigma0*(S/c0); P0 = G0^-1 Sigma0 ----
  for (int e = tid; e < 256; e += 64) Scl[e>>4][e&15] = Sm[e>>4][e&15]*invc0;
  WB();
  mm16w(B2, B1, Scl);
  for (int e = tid; e < 256; e += 64) { int a=e>>4,b=e&15; if (a==b) B2[a][b] += 1.f; }
  WB();
  float ld0 = inv16w(B2, B3);
  mm16w(B4, B3, B1);                        // B4 = P0
  float ldet_first = 0.5f*(64.f*logf(c0) + ld0);
  for (int e = tid; e < 256; e += 64) { wf[OFF_P0+e] = B4[e>>4][e&15]; wf[OFF_S+e] = Sm[e>>4][e&15]; }

  // ---- Riccati loop: P in B4 ----
  for (int e = tid; e < 256; e += 64) Scl[e>>4][e&15] = Sm[e>>4][e&15]*invc;
  WB();
  double dacc = 0.0; float ld_t = 0.f;
  #pragma unroll 1
  for (int t = 1; t <= NI; ++t) {
    mm16w(B6, Al, B4);                      // B6 = A*P
    mm16bt(B5, B6, Al);                     // B5 = A P A^T
    for (int e = tid; e < 256; e += 64) B5[e>>4][e&15] += Qm[e>>4][e&15];  // Sd
    WB();
    mm16w(B2, B5, Scl);                     // G = Sd*(S/c)
    for (int e = tid; e < 256; e += 64) { int a=e>>4,b=e&15; if (a==b) B2[a][b] += 1.f; }
    WB();
    float ldG = inv16w(B2, B3);             // B3 = G^-1
    mm16w(B4, B3, B5);                      // P = G^-1 Sd
    ld_t = 0.5f*(64.f*logf(c) + ldG);
    dacc += (double)ld_t;
  }
  double ldet_total = dacc + (double)(T_TOT-1-NI)*(double)ld_t;

  // ---- steady-state products ----
  mm16w(B1, Al, B3);                        // F = A G^-1  (last G^-1)
  mm16w(B6, Al, B4);                        // A*P_ss
  for (int e = tid; e < 256; e += 64) {
    wf[OFF_PSS+e] = B4[e>>4][e&15];
    wf[OFF_F+e]   = B1[e>>4][e&15];
    wf[OFF_KQ+e]  = B6[e>>4][e&15]*invc;
  }
  mm16w(B2, B1, B1);   // F^2
  mm16w(B5, B2, B2);   // F^4
  mm16w(B2, B5, B5);   // F^8
  mm16w(B5, B2, B2);   // F^16
  mm16w(B2, B5, B5);   // F^32
  mm16w(B5, B2, B2);   // F^64
  WB();
  for (int e = tid; e < 256; e += 64) wf[OFF_M64+e] = B5[e>>4][e&15];
  if (tid == 0) {
    double* d = (double*)wf;
    d[0] = (double)ldet_first;
    d[1] = ldet_total;
    wf[OFF_FS+0] = c0; wf[OFF_FS+1] = c; wf[OFF_FS+2] = invc; wf[OFF_FS+3] = invc0;
  }
}

// =====================================================================
// Pass A: chunk-local affine offsets, F-form: mud' = F*mud + Kq*q.
// block 256 = 16 trials x 16 lanes; grid (NCHUNK, 2).
// =====================================================================
__global__ __launch_bounds__(256) void k_passA()
{
  const int tid = threadIdx.x; const int j = tid & 15;
  const int n = blockIdx.y*16 + (tid >> 4);
  const int chunk = blockIdx.x;
  float* __restrict__ wf = g_wf;
  float Fr[16], Kr[16];
  #pragma unroll
  for (int k = 0; k < 16; ++k) {
    Fr[k] = wf[OFF_F  + j*16 + k];
    Kr[k] = wf[OFF_KQ + j*16 + k];
  }
  const int t0 = 1 + CHLEN*chunk;
  const int ns = (CHLEN < (T_TOT-1) - t0 + 1) ? CHLEN : ((T_TOT-1) - t0 + 1);
  const float* qp = wf + OFF_Q + (size_t)t0*512 + n*16 + j;
  float mud = 0.f;
  #pragma unroll 1
  for (int s = 0; s < ns; ++s) {
    float qj = qp[0]; qp += 512;
    float g; MV16(Kr, qj, g);
    float fm; MV16(Fr, mud, fm);
    mud = fm + g;
  }
  wf[OFF_VC + chunk*512 + n*16 + j] = mud;
}

// =====================================================================
// Pass B: t=0 term + serial scan over 128 chunk maps (one block, 512 thr).
// =====================================================================
__global__ __launch_bounds__(512) void k_passB(const float* __restrict__ A,
                                               const float* __restrict__ mu0)
{
  const int tid = threadIdx.x; const int j = tid & 15; const int n = tid >> 4;
  float* __restrict__ wf = g_wf;
  float Ar[16], Sr[16], P0r[16], M64r[16];
  #pragma unroll
  for (int k = 0; k < 16; ++k) {
    Ar[k]   = A[j*16+k];
    Sr[k]   = wf[OFF_S  + j*16 + k];
    P0r[k]  = wf[OFF_P0 + j*16 + k];
    M64r[k] = wf[OFF_M64+ j*16 + k];
  }
  const float c0 = wf[OFF_FS+0]; const float invc0 = wf[OFF_FS+3];
  float mu0j = mu0[j];
  float q0  = wf[OFF_Q + tid];       // t = 0
  float xx0 = wf[OFF_XX + n];
  float h0; MV16(Sr, mu0j, h0);
  float u0 = q0 - h0;
  float w0; MV16(P0r, u0, w0);
  float loc = fmaf(-2.f*q0, mu0j, fmaf(mu0j, h0, -(u0*w0*invc0)));
  RED16(loc);
  float fq = (xx0 + loc)*invc0;
  if (j == 0) wf[OFF_FQ + n] = fq;
  float muf = fmaf(w0, invc0, mu0j);
  float en; MV16(Ar, muf, en);       // entry_0 = mud_1 = A*muf0
  float vnext = wf[OFF_VC + tid];
  #pragma unroll 1
  for (int ii = 0; ii < NCHUNK; ++ii) {
    wf[OFF_EN + ii*512 + tid] = en;
    float vv = vnext;
    if (ii+1 < NCHUNK) vnext = wf[OFF_VC + (ii+1)*512 + tid];
    float nx; MV16(M64r, en, nx);
    en = nx + vv;
  }
}

// =====================================================================
// Pass C: replay chunks from true entries, accumulate LL quadratics.
// block 256 = 16 trials; grid (NCHUNK, 2).
// =====================================================================
__global__ __launch_bounds__(256) void k_passC(const float* __restrict__ A)
{
  const int tid = threadIdx.x; const int j = tid & 15;
  const int n = blockIdx.y*16 + (tid >> 4);
  const int chunk = blockIdx.x;
  float* __restrict__ wf = g_wf;
  float Ar[16], Sr[16], Pr[16];
  #pragma unroll
  for (int k = 0; k < 16; ++k) {
    Ar[k] = A[j*16+k];
    Sr[k] = wf[OFF_S  + j*16 + k];
    Pr[k] = wf[OFF_PSS+ j*16 + k];
  }
  const float invc = wf[OFF_FS+2];
  const int t0 = 1 + CHLEN*chunk;
  const int ns = (CHLEN < (T_TOT-1) - t0 + 1) ? CHLEN : ((T_TOT-1) - t0 + 1);
  const float* qp  = wf + OFF_Q  + (size_t)t0*512 + n*16 + j;
  const float* xxp = wf + OFF_XX + (size_t)t0*32 + n;
  float mud = wf[OFF_EN + chunk*512 + n*16 + j];
  float qacc = 0.f;
  #pragma unroll 1
  for (int s = 0; s < ns; ++s) {
    float qj = qp[0]; qp += 512;
    float xxv = xxp[0]; xxp += 32;
    float h; MV16(Sr, mud, h);
    float u = qj - h;
    float w; MV16(Pr, u, w);
    float loc = fmaf(-2.f*qj, mud, fmaf(mud, h, -(u*w*invc)));
    RED16(loc);
    qacc = fmaf(xxv + loc, invc, qacc);
    float tmp = fmaf(w, invc, mud);
    MV16(Ar, tmp, mud);
  }
  if (j == 0) wf[OFF_QS + chunk*32 + n] = qacc;
}

// =====================================================================
// Final assembly.
// =====================================================================
__global__ __launch_bounds__(64) void k_final(float* __restrict__ out)
{
  const int n = threadIdx.x;
  if (n >= NTR) return;
  const float* wf = g_wf;
  const double* dsc = (const double*)wf;
  double acc = (double)wf[OFF_FQ + n];
  for (int i = 0; i < NCHUNK; ++i) acc += (double)wf[OFF_QS + i*32 + n];
  const double LOG2PI = 1.8378770664093453;
  double ll = -32.0*LOG2PI*(double)T_TOT - dsc[0] - dsc[1] - 0.5*acc;
  out[n] = (float)ll;
}

extern "C" void kernel_launch(void* const* d_in, const int* in_sizes, int n_in,
                              void* d_out, int out_size, void* d_ws, size_t ws_size,
                              hipStream_t stream)
{
  (void)in_sizes; (void)n_in; (void)out_size; (void)d_ws; (void)ws_size;
  const float* v   = (const float*)d_in[0];
  const float* A   = (const float*)d_in[1];
  const float* B   = (const float*)d_in[2];
  const float* W   = (const float*)d_in[3];
  const float* mu0 = (const float*)d_in[4];
  const float* S0h = (const float*)d_in[5];
  const float* lsv = (const float*)d_in[6];
  float* out = (float*)d_out;

  k_front<<<1 + NTR*32, 256, 0, stream>>>(v, A, B, W, S0h, lsv);
  k_passA<<<dim3(NCHUNK,2), 256, 0, stream>>>();
  k_passB<<<1, 512, 0, stream>>>(A, mu0);
  k_passC<<<dim3(NCHUNK,2), 256, 0, stream>>>(A);
  k_final<<<1, 64, 0, stream>>>(out);
}

// Round 4
// 431.294 us; speedup vs baseline: 2.3635x; 1.3671x over previous
//
#include <hip/hip_runtime.h>
#include <math.h>

// Kalman forward LL: Woodbury reduction to 16-dim + steady-state Riccati
// (G = I + Sd*S/c, P = G^-1 Sd via augmented GJ, F = A - (A P/c) S)
// + chunked parallel scan over time for the mean recursion.

#define T_TOT 8192
#define NTR   32
#define VD    64
#define NCHUNK 128
#define CHLEN  64
#define NI     32     // exact Riccati iterations (then steady state); must be even

// ---- workspace layout (floats; doubles occupy wf[0..7]) ----
#define OFF_FS   8                        // c0, c, invc, invc0
#define OFF_S    16
#define OFF_P0   (OFF_S+256)
#define OFF_PSS  (OFF_P0+256)
#define OFF_F    (OFF_PSS+256)
#define OFF_M64  (OFF_F+256)
#define OFF_KQ   (OFF_M64+256)
#define OFF_FQ   (OFF_KQ+256)             // 32
#define OFF_VC   (OFF_FQ+32)              // NCHUNK*512
#define OFF_EN   (OFF_VC+NCHUNK*512)      // NCHUNK*512
#define OFF_QS   (OFF_EN+NCHUNK*512)      // NCHUNK*32
#define OFF_Q    (OFF_QS+NCHUNK*32)       // T_TOT*512
#define OFF_XX   (OFF_Q+T_TOT*512)        // T_TOT*32
#define WS_FLOATS (OFF_XX + T_TOT*32)

__device__ float g_wf[WS_FLOATS];

// ---- lane swizzle helpers (16-lane groups) ----
#define SWZ(x, imm) __int_as_float(__builtin_amdgcn_ds_swizzle(__float_as_int(x), (imm)))

// out_j = sum_k row[k] * v_k  (row = M[j][:] per-lane; v distributed lane j = comp j)
#define MV16(row, vv, out) do { \
  float b0_=SWZ(vv,0x010), b1_=SWZ(vv,0x030), b2_=SWZ(vv,0x050), b3_=SWZ(vv,0x070); \
  float b4_=SWZ(vv,0x090), b5_=SWZ(vv,0x0B0), b6_=SWZ(vv,0x0D0), b7_=SWZ(vv,0x0F0); \
  float b8_=SWZ(vv,0x110), b9_=SWZ(vv,0x130), b10_=SWZ(vv,0x150), b11_=SWZ(vv,0x170); \
  float b12_=SWZ(vv,0x190), b13_=SWZ(vv,0x1B0), b14_=SWZ(vv,0x1D0), b15_=SWZ(vv,0x1F0); \
  float s0_=fmaf((row)[0],b0_,fmaf((row)[1],b1_,fmaf((row)[2],b2_,(row)[3]*b3_))); \
  float s1_=fmaf((row)[4],b4_,fmaf((row)[5],b5_,fmaf((row)[6],b6_,(row)[7]*b7_))); \
  float s2_=fmaf((row)[8],b8_,fmaf((row)[9],b9_,fmaf((row)[10],b10_,(row)[11]*b11_))); \
  float s3_=fmaf((row)[12],b12_,fmaf((row)[13],b13_,fmaf((row)[14],b14_,(row)[15]*b15_))); \
  (out)=(s0_+s1_)+(s2_+s3_); \
} while(0)

// full 16-lane-group sum (result in all 16 lanes)
#define RED16(x) do { x+=SWZ(x,0x041F); x+=SWZ(x,0x081F); x+=SWZ(x,0x101F); x+=SWZ(x,0x201F); } while(0)

// =====================================================================
// K0: q[t][n][:] = W^T x_{t,n},  xx[t][n] = ||x||^2.  2 t-values/thread.
// =====================================================================
__global__ __launch_bounds__(256) void k_q(const float* __restrict__ v,
                                           const float* __restrict__ W)
{
  __shared__ float Wl[VD][16];
  const int tid = threadIdx.x;
  for (int e = tid; e < VD*16; e += 256) Wl[e>>4][e&15] = W[e];
  __syncthreads();
  const int n = blockIdx.y;
  const int t0 = (blockIdx.x*256 + tid)*2;
  const float* vp = v + (size_t)n*VD*T_TOT + t0;
  float a0[16], a1[16];
  #pragma unroll
  for (int k = 0; k < 16; ++k) { a0[k] = 0.f; a1[k] = 0.f; }
  float s20 = 0.f, s21 = 0.f;
  #pragma unroll 4
  for (int i2 = 0; i2 < VD; ++i2) {
    float2 x = *(const float2*)&vp[(size_t)i2*T_TOT];
    s20 = fmaf(x.x, x.x, s20); s21 = fmaf(x.y, x.y, s21);
    const float4* wr = (const float4*)&Wl[i2][0];
    float4 w0 = wr[0], w1 = wr[1], w2 = wr[2], w3 = wr[3];
    a0[0]=fmaf(x.x,w0.x,a0[0]);  a1[0]=fmaf(x.y,w0.x,a1[0]);
    a0[1]=fmaf(x.x,w0.y,a0[1]);  a1[1]=fmaf(x.y,w0.y,a1[1]);
    a0[2]=fmaf(x.x,w0.z,a0[2]);  a1[2]=fmaf(x.y,w0.z,a1[2]);
    a0[3]=fmaf(x.x,w0.w,a0[3]);  a1[3]=fmaf(x.y,w0.w,a1[3]);
    a0[4]=fmaf(x.x,w1.x,a0[4]);  a1[4]=fmaf(x.y,w1.x,a1[4]);
    a0[5]=fmaf(x.x,w1.y,a0[5]);  a1[5]=fmaf(x.y,w1.y,a1[5]);
    a0[6]=fmaf(x.x,w1.z,a0[6]);  a1[6]=fmaf(x.y,w1.z,a1[6]);
    a0[7]=fmaf(x.x,w1.w,a0[7]);  a1[7]=fmaf(x.y,w1.w,a1[7]);
    a0[8]=fmaf(x.x,w2.x,a0[8]);  a1[8]=fmaf(x.y,w2.x,a1[8]);
    a0[9]=fmaf(x.x,w2.y,a0[9]);  a1[9]=fmaf(x.y,w2.y,a1[9]);
    a0[10]=fmaf(x.x,w2.z,a0[10]); a1[10]=fmaf(x.y,w2.z,a1[10]);
    a0[11]=fmaf(x.x,w2.w,a0[11]); a1[11]=fmaf(x.y,w2.w,a1[11]);
    a0[12]=fmaf(x.x,w3.x,a0[12]); a1[12]=fmaf(x.y,w3.x,a1[12]);
    a0[13]=fmaf(x.x,w3.y,a0[13]); a1[13]=fmaf(x.y,w3.y,a1[13]);
    a0[14]=fmaf(x.x,w3.z,a0[14]); a1[14]=fmaf(x.y,w3.z,a1[14]);
    a0[15]=fmaf(x.x,w3.w,a0[15]); a1[15]=fmaf(x.y,w3.w,a1[15]);
  }
  float4* q0 = (float4*)(g_wf + OFF_Q + ((size_t)t0*32 + n)*16);
  q0[0] = make_float4(a0[0],a0[1],a0[2],a0[3]);
  q0[1] = make_float4(a0[4],a0[5],a0[6],a0[7]);
  q0[2] = make_float4(a0[8],a0[9],a0[10],a0[11]);
  q0[3] = make_float4(a0[12],a0[13],a0[14],a0[15]);
  float4* q1 = (float4*)(g_wf + OFF_Q + ((size_t)(t0+1)*32 + n)*16);
  q1[0] = make_float4(a1[0],a1[1],a1[2],a1[3]);
  q1[1] = make_float4(a1[4],a1[5],a1[6],a1[7]);
  q1[2] = make_float4(a1[8],a1[9],a1[10],a1[11]);
  q1[3] = make_float4(a1[12],a1[13],a1[14],a1[15]);
  g_wf[OFF_XX + (size_t)t0*32 + n]     = s20;
  g_wf[OFF_XX + (size_t)(t0+1)*32 + n] = s21;
}

// =====================================================================
// 16x16 block primitives (64 threads; thread = row i, col group c4).
// In-place safe: all reads complete before the mid-barrier, writes after.
// =====================================================================
__device__ __forceinline__ void mm16(float (*C)[16], float (*Aa)[16], float (*Bb)[16])
{
  const int tid = threadIdx.x; const int i = tid>>2; const int c4 = (tid&3)<<2;
  __syncthreads();
  float a0=0.f,a1=0.f,a2=0.f,a3=0.f;
  #pragma unroll
  for (int k = 0; k < 16; ++k) {
    float a = Aa[i][k];
    a0=fmaf(a,Bb[k][c4+0],a0); a1=fmaf(a,Bb[k][c4+1],a1);
    a2=fmaf(a,Bb[k][c4+2],a2); a3=fmaf(a,Bb[k][c4+3],a3);
  }
  __syncthreads();
  C[i][c4+0]=a0; C[i][c4+1]=a1; C[i][c4+2]=a2; C[i][c4+3]=a3;
  __syncthreads();
}

__device__ __forceinline__ void mm16bt(float (*C)[16], float (*Aa)[16], float (*Bb)[16])
{
  const int tid = threadIdx.x; const int i = tid>>2; const int c4 = (tid&3)<<2;
  __syncthreads();
  float a0=0.f,a1=0.f,a2=0.f,a3=0.f;
  #pragma unroll
  for (int k = 0; k < 16; ++k) {
    float a = Aa[i][k];
    a0=fmaf(a,Bb[c4+0][k],a0); a1=fmaf(a,Bb[c4+1][k],a1);
    a2=fmaf(a,Bb[c4+2][k],a2); a3=fmaf(a,Bb[c4+3][k],a3);
  }
  __syncthreads();
  C[i][c4+0]=a0; C[i][c4+1]=a1; C[i][c4+2]=a2; C[i][c4+3]=a3;
  __syncthreads();
}

// Augmented GJ: M -> I, R -> M^{-1} R; returns log|det M| (all lanes).
// Fully unrolled pivots (critical for ds_read overlap).
__device__ float gj16(float (*Mw)[16], float (*Rw)[16])
{
  const int tid = threadIdx.x; const int i = tid>>2; const int c4 = (tid&3)<<2;
  __syncthreads();
  float ld = 0.f;
  #pragma unroll
  for (int k = 0; k < 16; ++k) {
    float p = Mw[k][k];
    ld += logf(fabsf(p));
    float r = 1.f/p;
    float mk0=Mw[k][c4+0], mk1=Mw[k][c4+1], mk2=Mw[k][c4+2], mk3=Mw[k][c4+3];
    float rk0=Rw[k][c4+0], rk1=Rw[k][c4+1], rk2=Rw[k][c4+2], rk3=Rw[k][c4+3];
    float f = Mw[i][k]*r;
    __syncthreads();
    if (i == k) {
      Mw[k][c4+0]=mk0*r; Mw[k][c4+1]=mk1*r; Mw[k][c4+2]=mk2*r; Mw[k][c4+3]=mk3*r;
      Rw[k][c4+0]=rk0*r; Rw[k][c4+1]=rk1*r; Rw[k][c4+2]=rk2*r; Rw[k][c4+3]=rk3*r;
    } else {
      Mw[i][c4+0]-=f*mk0; Mw[i][c4+1]-=f*mk1; Mw[i][c4+2]-=f*mk2; Mw[i][c4+3]-=f*mk3;
      Rw[i][c4+0]-=f*rk0; Rw[i][c4+1]-=f*rk1; Rw[i][c4+2]-=f*rk2; Rw[i][c4+3]-=f*rk3;
    }
    __syncthreads();
  }
  return ld;
}

// =====================================================================
// K1: Riccati covariance recursion (1 block, 64 threads).
// =====================================================================
__global__ __launch_bounds__(64) void k_cov(const float* __restrict__ A,
                                            const float* __restrict__ B,
                                            const float* __restrict__ W,
                                            const float* __restrict__ S0h,
                                            const float* __restrict__ lsv)
{
  __shared__ float Wl[VD][16];
  __shared__ float Al[16][16], Sm[16][16], Qm[16][16], Scl[16][16];
  __shared__ float B1[16][16], B2[16][16], B4[16][16], B5[16][16], B6[16][16];
  const int tid = threadIdx.x;
  float* __restrict__ wf = g_wf;

  for (int e = tid; e < VD*16; e += 64) Wl[e>>4][e&15] = W[e];
  for (int e = tid; e < 256; e += 64) Al[e>>4][e&15] = A[e];
  __syncthreads();
  for (int e = tid; e < 256; e += 64) {
    int a = e>>4, b = e&15; float s = 0.f;
    for (int r = 0; r < VD; ++r) s = fmaf(Wl[r][a], Wl[r][b], s);
    Sm[a][b] = s;
  }
  for (int e = tid; e < 256; e += 64) {
    int a = e>>4, b = e&15; float s = (a==b)?1e-6f:0.f;
    int m = a < b ? a : b;
    for (int r = 0; r <= m; ++r) s = fmaf(B[a*16+r], B[b*16+r], s);
    Qm[a][b] = s;
  }
  for (int e = tid; e < 256; e += 64) {          // B1 = Sigma0
    int a = e>>4, b = e&15; float s = (a==b)?1e-6f:0.f;
    int m = a < b ? a : b;
    for (int r = 0; r <= m; ++r) s = fmaf(S0h[a*16+r], S0h[b*16+r], s);
    B1[a][b] = s;
  }
  __syncthreads();
  float ev = expf(lsv[0]); float var = ev*ev;
  float c0 = var + 1e-6f, c = var + 2e-6f;
  float invc0 = 1.f/c0, invc = 1.f/c;

  // ---- t=0: G0 = I + Sigma0*(S/c0); P0 = G0^-1 Sigma0 ----
  for (int e = tid; e < 256; e += 64) Scl[e>>4][e&15] = Sm[e>>4][e&15]*invc0;
  mm16(B2, B1, Scl);
  for (int e = tid; e < 256; e += 64) { int a=e>>4,b=e&15; if (a==b) B2[a][b] += 1.f; }
  float ld0 = gj16(B2, B1);                      // B1 := P0
  float ldet_first = 0.5f*(64.f*logf(c0) + ld0);
  for (int e = tid; e < 256; e += 64) { wf[OFF_P0+e] = B1[e>>4][e&15]; wf[OFF_S+e] = Sm[e>>4][e&15]; }
  for (int e = tid; e < 256; e += 64) { B4[e>>4][e&15] = B1[e>>4][e&15]; Scl[e>>4][e&15] = Sm[e>>4][e&15]*invc; }

  // ---- Riccati loop (unrolled x2 to ping-pong P between B4/B5) ----
  double dacc = 0.0; float ld_t = 0.f;

#define RSTEP(Pin, Pout) do { \
    mm16(B6, Al, Pin);                 /* A P           */ \
    mm16bt(Pout, B6, Al);              /* A P A^T       */ \
    for (int e = tid; e < 256; e += 64) Pout[e>>4][e&15] += Qm[e>>4][e&15]; /* Sd */ \
    mm16(B2, Pout, Scl);               /* Sd S/c        */ \
    for (int e = tid; e < 256; e += 64) { int a=e>>4,b=e&15; if (a==b) B2[a][b] += 1.f; } \
    float ldG = gj16(B2, Pout);        /* Pout := P_new */ \
    ld_t = 0.5f*(64.f*logf(c) + ldG); \
    dacc += (double)ld_t; \
  } while(0)

  #pragma unroll 1
  for (int t = 0; t < NI; t += 2) {
    RSTEP(B4, B5);
    RSTEP(B5, B4);
  }
#undef RSTEP
  double ldet_total = dacc + (double)(T_TOT-1-NI)*(double)ld_t;

  // ---- steady-state products: Kq = A P/c ; F = A - Kq S ----
  mm16(B6, Al, B4);                    // A P_ss
  for (int e = tid; e < 256; e += 64) B6[e>>4][e&15] *= invc;   // Kq
  __syncthreads();
  mm16(B1, B6, Sm);                    // Kq S
  for (int e = tid; e < 256; e += 64) { int a=e>>4,b=e&15; B2[a][b] = Al[a][b] - B1[a][b]; }  // F
  __syncthreads();
  for (int e = tid; e < 256; e += 64) {
    wf[OFF_PSS+e] = B4[e>>4][e&15];
    wf[OFF_F+e]   = B2[e>>4][e&15];
    wf[OFF_KQ+e]  = B6[e>>4][e&15];
  }
  mm16(B5, B2, B2);   // F^2
  mm16(B2, B5, B5);   // F^4
  mm16(B5, B2, B2);   // F^8
  mm16(B2, B5, B5);   // F^16
  mm16(B5, B2, B2);   // F^32
  mm16(B2, B5, B5);   // F^64
  for (int e = tid; e < 256; e += 64) wf[OFF_M64+e] = B2[e>>4][e&15];
  if (tid == 0) {
    double* d = (double*)wf;
    d[0] = (double)ldet_first;
    d[1] = ldet_total;
    wf[OFF_FS+0] = c0; wf[OFF_FS+1] = c; wf[OFF_FS+2] = invc; wf[OFF_FS+3] = invc0;
  }
}

// =====================================================================
// Pass A: chunk-local affine offsets, F-form: mud' = F*mud + Kq*q.
// block 256 = 16 trials x 16 lanes; grid (NCHUNK, 2).
// =====================================================================
__global__ __launch_bounds__(256) void k_passA()
{
  const int tid = threadIdx.x; const int j = tid & 15;
  const int n = blockIdx.y*16 + (tid >> 4);
  const int chunk = blockIdx.x;
  float* __restrict__ wf = g_wf;
  float Fr[16], Kr[16];
  #pragma unroll
  for (int k = 0; k < 16; ++k) {
    Fr[k] = wf[OFF_F  + j*16 + k];
    Kr[k] = wf[OFF_KQ + j*16 + k];
  }
  const int t0 = 1 + CHLEN*chunk;
  const int ns = (CHLEN < (T_TOT-1) - t0 + 1) ? CHLEN : ((T_TOT-1) - t0 + 1);
  const float* qp = wf + OFF_Q + (size_t)t0*512 + n*16 + j;
  float mud = 0.f;
  #pragma unroll 1
  for (int s = 0; s < ns; ++s) {
    float qj = qp[0]; qp += 512;
    float g; MV16(Kr, qj, g);
    float fm; MV16(Fr, mud, fm);
    mud = fm + g;
  }
  wf[OFF_VC + chunk*512 + n*16 + j] = mud;
}

// =====================================================================
// Pass B: t=0 term + serial scan over 128 chunk maps (one block, 512 thr).
// =====================================================================
__global__ __launch_bounds__(512) void k_passB(const float* __restrict__ A,
                                               const float* __restrict__ mu0)
{
  const int tid = threadIdx.x; const int j = tid & 15; const int n = tid >> 4;
  float* __restrict__ wf = g_wf;
  float Ar[16], Sr[16], P0r[16], M64r[16];
  #pragma unroll
  for (int k = 0; k < 16; ++k) {
    Ar[k]   = A[j*16+k];
    Sr[k]   = wf[OFF_S  + j*16 + k];
    P0r[k]  = wf[OFF_P0 + j*16 + k];
    M64r[k] = wf[OFF_M64+ j*16 + k];
  }
  const float c0 = wf[OFF_FS+0]; const float invc0 = wf[OFF_FS+3];
  float mu0j = mu0[j];
  float q0  = wf[OFF_Q + tid];       // t = 0
  float xx0 = wf[OFF_XX + n];
  float h0; MV16(Sr, mu0j, h0);
  float u0 = q0 - h0;
  float w0; MV16(P0r, u0, w0);
  float loc = fmaf(-2.f*q0, mu0j, fmaf(mu0j, h0, -(u0*w0*invc0)));
  RED16(loc);
  float fq = (xx0 + loc)*invc0;
  if (j == 0) wf[OFF_FQ + n] = fq;
  float muf = fmaf(w0, invc0, mu0j);
  float en; MV16(Ar, muf, en);       // entry_0 = mud_1 = A*muf0
  float vnext = wf[OFF_VC + tid];
  #pragma unroll 1
  for (int ii = 0; ii < NCHUNK; ++ii) {
    wf[OFF_EN + ii*512 + tid] = en;
    float vv = vnext;
    if (ii+1 < NCHUNK) vnext = wf[OFF_VC + (ii+1)*512 + tid];
    float nx; MV16(M64r, en, nx);
    en = nx + vv;
  }
}

// =====================================================================
// Pass C: replay chunks from true entries, accumulate LL quadratics.
// block 256 = 16 trials; grid (NCHUNK, 2).
// =====================================================================
__global__ __launch_bounds__(256) void k_passC(const float* __restrict__ A)
{
  const int tid = threadIdx.x; const int j = tid & 15;
  const int n = blockIdx.y*16 + (tid >> 4);
  const int chunk = blockIdx.x;
  float* __restrict__ wf = g_wf;
  float Ar[16], Sr[16], Pr[16];
  #pragma unroll
  for (int k = 0; k < 16; ++k) {
    Ar[k] = A[j*16+k];
    Sr[k] = wf[OFF_S  + j*16 + k];
    Pr[k] = wf[OFF_PSS+ j*16 + k];
  }
  const float invc = wf[OFF_FS+2];
  const int t0 = 1 + CHLEN*chunk;
  const int ns = (CHLEN < (T_TOT-1) - t0 + 1) ? CHLEN : ((T_TOT-1) - t0 + 1);
  const float* qp  = wf + OFF_Q  + (size_t)t0*512 + n*16 + j;
  const float* xxp = wf + OFF_XX + (size_t)t0*32 + n;
  float mud = wf[OFF_EN + chunk*512 + n*16 + j];
  float qacc = 0.f;
  #pragma unroll 1
  for (int s = 0; s < ns; ++s) {
    float qj = qp[0]; qp += 512;
    float xxv = xxp[0]; xxp += 32;
    float h; MV16(Sr, mud, h);
    float u = qj - h;
    float w; MV16(Pr, u, w);
    float loc = fmaf(-2.f*qj, mud, fmaf(mud, h, -(u*w*invc)));
    RED16(loc);
    qacc = fmaf(xxv + loc, invc, qacc);
    float tmp = fmaf(w, invc, mud);
    MV16(Ar, tmp, mud);
  }
  if (j == 0) wf[OFF_QS + chunk*32 + n] = qacc;
}

// =====================================================================
// Final assembly.
// =====================================================================
__global__ __launch_bounds__(64) void k_final(float* __restrict__ out)
{
  const int n = threadIdx.x;
  if (n >= NTR) return;
  const float* wf = g_wf;
  const double* dsc = (const double*)wf;
  double acc = (double)wf[OFF_FQ + n];
  for (int i = 0; i < NCHUNK; ++i) acc += (double)wf[OFF_QS + i*32 + n];
  const double LOG2PI = 1.8378770664093453;
  double ll = -32.0*LOG2PI*(double)T_TOT - dsc[0] - dsc[1] - 0.5*acc;
  out[n] = (float)ll;
}

extern "C" void kernel_launch(void* const* d_in, const int* in_sizes, int n_in,
                              void* d_out, int out_size, void* d_ws, size_t ws_size,
                              hipStream_t stream)
{
  (void)in_sizes; (void)n_in; (void)out_size; (void)d_ws; (void)ws_size;
  const float* v   = (const float*)d_in[0];
  const float* A   = (const float*)d_in[1];
  const float* B   = (const float*)d_in[2];
  const float* W   = (const float*)d_in[3];
  const float* mu0 = (const float*)d_in[4];
  const float* S0h = (const float*)d_in[5];
  const float* lsv = (const float*)d_in[6];
  float* out = (float*)d_out;

  k_q    <<<dim3(T_TOT/512, NTR), 256, 0, stream>>>(v, W);
  k_cov  <<<1, 64, 0, stream>>>(A, B, W, S0h, lsv);
  k_passA<<<dim3(NCHUNK,2), 256, 0, stream>>>();
  k_passB<<<1, 512, 0, stream>>>(A, mu0);
  k_passC<<<dim3(NCHUNK,2), 256, 0, stream>>>(A);
  k_final<<<1, 64, 0, stream>>>(out);
}

// Round 5
// 218.745 us; speedup vs baseline: 4.6601x; 1.9717x over previous
//
#include <hip/hip_runtime.h>
#include <math.h>

// Kalman forward LL: Woodbury 16-dim reduction + steady-state Riccati
// (G = I + Sd*S/c, 1-barrier GJ solve, F = A - Kq S) + parallel chunked
// scan (entry reconstruction via M64 powers; no serial passB).

#define T_TOT 8192
#define NTR   32
#define VD    64
#define NCHUNK 128
#define CHLEN  64
#define NI     12     // exact Riccati iterations (even), then steady state

// ---- workspace layout (floats; doubles occupy wf[0..7]) ----
#define OFF_FS    8
#define OFF_S     16
#define OFF_P0    272
#define OFF_PSS   528
#define OFF_F     784
#define OFF_M64   1040
#define OFF_M128  1296
#define OFF_KQ    1552
#define OFF_EN0   1808
#define OFF_FQ    2320
#define OFF_VC    2352                    // NCHUNK*512
#define OFF_QS    67888                   // NCHUNK*32
#define OFF_Q     71984                   // [n][t][16]
#define OFF_XX    4266288                 // [n][t]
#define WS_FLOATS 4528432

__device__ float g_wf[WS_FLOATS];

// ---- lane swizzle helpers (16-lane groups) ----
#define SWZ(x, imm) __int_as_float(__builtin_amdgcn_ds_swizzle(__float_as_int(x), (imm)))

#define MV16(row, vv, out) do { \
  float b0_=SWZ(vv,0x010), b1_=SWZ(vv,0x030), b2_=SWZ(vv,0x050), b3_=SWZ(vv,0x070); \
  float b4_=SWZ(vv,0x090), b5_=SWZ(vv,0x0B0), b6_=SWZ(vv,0x0D0), b7_=SWZ(vv,0x0F0); \
  float b8_=SWZ(vv,0x110), b9_=SWZ(vv,0x130), b10_=SWZ(vv,0x150), b11_=SWZ(vv,0x170); \
  float b12_=SWZ(vv,0x190), b13_=SWZ(vv,0x1B0), b14_=SWZ(vv,0x1D0), b15_=SWZ(vv,0x1F0); \
  float s0_=fmaf((row)[0],b0_,fmaf((row)[1],b1_,fmaf((row)[2],b2_,(row)[3]*b3_))); \
  float s1_=fmaf((row)[4],b4_,fmaf((row)[5],b5_,fmaf((row)[6],b6_,(row)[7]*b7_))); \
  float s2_=fmaf((row)[8],b8_,fmaf((row)[9],b9_,fmaf((row)[10],b10_,(row)[11]*b11_))); \
  float s3_=fmaf((row)[12],b12_,fmaf((row)[13],b13_,fmaf((row)[14],b14_,(row)[15]*b15_))); \
  (out)=(s0_+s1_)+(s2_+s3_); \
} while(0)

#define RED16(x) do { x+=SWZ(x,0x041F); x+=SWZ(x,0x081F); x+=SWZ(x,0x101F); x+=SWZ(x,0x201F); } while(0)

// =====================================================================
// 16x16 primitives for 256 threads: ri = tid>>4 (row), ci = tid&15 (col).
// =====================================================================
__device__ __forceinline__ void mm16(float (*C)[16], float (*Aa)[16], float (*Bb)[16],
                                     int ri, int ci)
{
  __syncthreads();
  float a = 0.f;
  #pragma unroll
  for (int k = 0; k < 16; ++k) a = fmaf(Aa[ri][k], Bb[k][ci], a);
  __syncthreads();
  C[ri][ci] = a;
  __syncthreads();
}

__device__ __forceinline__ void mm16bt(float (*C)[16], float (*Aa)[16], float (*Bb)[16],
                                       int ri, int ci)
{
  __syncthreads();
  float a = 0.f;
  #pragma unroll
  for (int k = 0; k < 16; ++k) a = fmaf(Aa[ri][k], Bb[ci][k], a);
  __syncthreads();
  C[ri][ci] = a;
  __syncthreads();
}

// 1-barrier-per-pivot GJ: no pivot-row normalization during elimination
// (row k untouched at pivot k); final normalize by preserved diagonal.
// M -> diag, R -> M^{-1} R (normalized). Returns log|det M|.
__device__ float gj16(float (*Mw)[16], float (*Rw)[16], int ri, int ci)
{
  __syncthreads();
  float ld = 0.f;
  #pragma unroll
  for (int k = 0; k < 16; ++k) {
    float p = Mw[k][k];
    ld += logf(fabsf(p));
    float r = 1.f/p;
    float fik = Mw[ri][k];     // row-local (same wave as any write to row ri)
    float mk = Mw[k][ci];
    float rk = Rw[k][ci];
    float f = fik * r;
    if (ri != k) {
      Mw[ri][ci] -= f*mk;      // ci==k lane writes the exact 0 of column elim
      Rw[ri][ci] -= f*rk;
    }
    __syncthreads();
  }
  float res = Rw[ri][ci] / Mw[ri][ri];
  __syncthreads();
  Rw[ri][ci] = res;
  __syncthreads();
  return ld;
}

// =====================================================================
// Fused front: block 0 = Riccati (256 thr); blocks >=1 = q/xx pass.
// =====================================================================
__global__ __launch_bounds__(256) void k_front(const float* __restrict__ v,
                                               const float* __restrict__ A,
                                               const float* __restrict__ B,
                                               const float* __restrict__ W,
                                               const float* __restrict__ S0h,
                                               const float* __restrict__ lsv)
{
  __shared__ float Wl[VD][16];
  __shared__ float Al[16][16], Sm[16][16], Qm[16][16], Scl[16][16];
  __shared__ float B1[16][16], B2[16][16], B4[16][16], B5[16][16], B6[16][16];
  const int tid = threadIdx.x;
  float* __restrict__ wf = g_wf;

  if (blockIdx.x != 0) {
    // ---------------- q-pass: q = W^T x, xx = ||x||^2 ----------------
    for (int e = tid; e < VD*16; e += 256) Wl[e>>4][e&15] = W[e];
    __syncthreads();
    const int bid = blockIdx.x - 1;
    const int n = bid >> 4;
    const int t0 = (bid & 15)*512 + tid*2;
    const float* vp = v + (size_t)n*VD*T_TOT + t0;
    float a0[16], a1[16];
    #pragma unroll
    for (int k = 0; k < 16; ++k) { a0[k] = 0.f; a1[k] = 0.f; }
    float s20 = 0.f, s21 = 0.f;
    #pragma unroll 4
    for (int i2 = 0; i2 < VD; ++i2) {
      float2 x = *(const float2*)&vp[(size_t)i2*T_TOT];
      s20 = fmaf(x.x, x.x, s20); s21 = fmaf(x.y, x.y, s21);
      const float4* wr = (const float4*)&Wl[i2][0];
      float4 w0 = wr[0], w1 = wr[1], w2 = wr[2], w3 = wr[3];
      a0[0]=fmaf(x.x,w0.x,a0[0]);  a1[0]=fmaf(x.y,w0.x,a1[0]);
      a0[1]=fmaf(x.x,w0.y,a0[1]);  a1[1]=fmaf(x.y,w0.y,a1[1]);
      a0[2]=fmaf(x.x,w0.z,a0[2]);  a1[2]=fmaf(x.y,w0.z,a1[2]);
      a0[3]=fmaf(x.x,w0.w,a0[3]);  a1[3]=fmaf(x.y,w0.w,a1[3]);
      a0[4]=fmaf(x.x,w1.x,a0[4]);  a1[4]=fmaf(x.y,w1.x,a1[4]);
      a0[5]=fmaf(x.x,w1.y,a0[5]);  a1[5]=fmaf(x.y,w1.y,a1[5]);
      a0[6]=fmaf(x.x,w1.z,a0[6]);  a1[6]=fmaf(x.y,w1.z,a1[6]);
      a0[7]=fmaf(x.x,w1.w,a0[7]);  a1[7]=fmaf(x.y,w1.w,a1[7]);
      a0[8]=fmaf(x.x,w2.x,a0[8]);  a1[8]=fmaf(x.y,w2.x,a1[8]);
      a0[9]=fmaf(x.x,w2.y,a0[9]);  a1[9]=fmaf(x.y,w2.y,a1[9]);
      a0[10]=fmaf(x.x,w2.z,a0[10]); a1[10]=fmaf(x.y,w2.z,a1[10]);
      a0[11]=fmaf(x.x,w2.w,a0[11]); a1[11]=fmaf(x.y,w2.w,a1[11]);
      a0[12]=fmaf(x.x,w3.x,a0[12]); a1[12]=fmaf(x.y,w3.x,a1[12]);
      a0[13]=fmaf(x.x,w3.y,a0[13]); a1[13]=fmaf(x.y,w3.y,a1[13]);
      a0[14]=fmaf(x.x,w3.z,a0[14]); a1[14]=fmaf(x.y,w3.z,a1[14]);
      a0[15]=fmaf(x.x,w3.w,a0[15]); a1[15]=fmaf(x.y,w3.w,a1[15]);
    }
    float4* q0 = (float4*)(wf + OFF_Q + (size_t)n*131072 + (size_t)t0*16);
    q0[0] = make_float4(a0[0],a0[1],a0[2],a0[3]);
    q0[1] = make_float4(a0[4],a0[5],a0[6],a0[7]);
    q0[2] = make_float4(a0[8],a0[9],a0[10],a0[11]);
    q0[3] = make_float4(a0[12],a0[13],a0[14],a0[15]);
    q0[4] = make_float4(a1[0],a1[1],a1[2],a1[3]);
    q0[5] = make_float4(a1[4],a1[5],a1[6],a1[7]);
    q0[6] = make_float4(a1[8],a1[9],a1[10],a1[11]);
    q0[7] = make_float4(a1[12],a1[13],a1[14],a1[15]);
    wf[OFF_XX + (size_t)n*T_TOT + t0]     = s20;
    wf[OFF_XX + (size_t)n*T_TOT + t0 + 1] = s21;
    return;
  }

  // ---------------- Riccati (256 threads, elem-per-thread) ----------------
  const int ri = tid >> 4, ci = tid & 15;
  for (int e = tid; e < VD*16; e += 256) Wl[e>>4][e&15] = W[e];
  Al[ri][ci] = A[tid];
  __syncthreads();
  {
    float s = 0.f;
    for (int r = 0; r < VD; ++r) s = fmaf(Wl[r][ri], Wl[r][ci], s);
    Sm[ri][ci] = s;
    int m = ri < ci ? ri : ci;
    float q = (ri==ci)?1e-6f:0.f, g0 = (ri==ci)?1e-6f:0.f;
    for (int r = 0; r <= m; ++r) {
      q  = fmaf(B[ri*16+r],   B[ci*16+r],   q);
      g0 = fmaf(S0h[ri*16+r], S0h[ci*16+r], g0);
    }
    Qm[ri][ci] = q;
    B1[ri][ci] = g0;                         // Sigma0
  }
  __syncthreads();
  float ev = expf(lsv[0]); float var = ev*ev;
  float c0v = var + 1e-6f, cv = var + 2e-6f;
  float invc0 = 1.f/c0v, invc = 1.f/cv;

  // t=0: G0 = I + Sigma0*(S/c0); P0 = G0^-1 Sigma0
  Scl[ri][ci] = Sm[ri][ci]*invc0;
  mm16(B2, B1, Scl, ri, ci);
  if (ri == ci) B2[ri][ci] += 1.f;
  float ld0 = gj16(B2, B1, ri, ci);          // B1 := P0
  float ldet_first = 0.5f*(64.f*logf(c0v) + ld0);
  wf[OFF_P0 + tid] = B1[ri][ci];
  wf[OFF_S  + tid] = Sm[ri][ci];
  B4[ri][ci] = B1[ri][ci];
  Scl[ri][ci] = Sm[ri][ci]*invc;

  double dacc = 0.0; float ld_t = 0.f;
#define RSTEP(Pin, Pout) do { \
    mm16(B6, Al, Pin, ri, ci); \
    mm16bt(Pout, B6, Al, ri, ci); \
    Pout[ri][ci] += Qm[ri][ci];              /* Sd (owner-exclusive) */ \
    mm16(B2, Pout, Scl, ri, ci); \
    if (ri == ci) B2[ri][ci] += 1.f; \
    float ldG = gj16(B2, Pout, ri, ci);      /* Pout := P_new */ \
    ld_t = 0.5f*(64.f*logf(cv) + ldG); \
    dacc += (double)ld_t; \
  } while(0)

  #pragma unroll 1
  for (int t = 0; t < NI; t += 2) {
    RSTEP(B4, B5);
    RSTEP(B5, B4);
  }
#undef RSTEP
  double ldet_total = dacc + (double)(T_TOT-1-NI)*(double)ld_t;

  // steady state: Kq = A P/c ; F = A - Kq S ; powers of F
  mm16(B6, Al, B4, ri, ci);
  B6[ri][ci] *= invc;                        // Kq
  mm16(B1, B6, Sm, ri, ci);
  B2[ri][ci] = Al[ri][ci] - B1[ri][ci];      // F
  __syncthreads();
  wf[OFF_PSS + tid] = B4[ri][ci];
  wf[OFF_F   + tid] = B2[ri][ci];
  wf[OFF_KQ  + tid] = B6[ri][ci];
  mm16(B5, B2, B2, ri, ci);   // F^2
  mm16(B2, B5, B5, ri, ci);   // F^4
  mm16(B5, B2, B2, ri, ci);   // F^8
  mm16(B2, B5, B5, ri, ci);   // F^16
  mm16(B5, B2, B2, ri, ci);   // F^32
  mm16(B2, B5, B5, ri, ci);   // F^64
  wf[OFF_M64 + tid] = B2[ri][ci];
  mm16(B5, B2, B2, ri, ci);   // F^128
  wf[OFF_M128 + tid] = B5[ri][ci];
  if (tid == 0) {
    double* d = (double*)wf;
    d[0] = (double)ldet_first;
    d[1] = ldet_total;
    wf[OFF_FS+0] = c0v; wf[OFF_FS+1] = cv; wf[OFF_FS+2] = invc; wf[OFF_FS+3] = invc0;
  }
}

// =====================================================================
// Pass A: chunk-local offsets (F-form) + t0-term block (x == NCHUNK).
// =====================================================================
__global__ __launch_bounds__(256) void k_passA(const float* __restrict__ A,
                                               const float* __restrict__ mu0)
{
  const int tid = threadIdx.x; const int j = tid & 15;
  const int n = blockIdx.y*16 + (tid >> 4);
  float* __restrict__ wf = g_wf;

  if (blockIdx.x == NCHUNK) {
    // ---- t=0 term + en0 = A*muf0 ----
    float Ar[16], Sr[16], P0r[16];
    #pragma unroll
    for (int k = 0; k < 16; ++k) {
      Ar[k]  = A[j*16+k];
      Sr[k]  = wf[OFF_S  + j*16 + k];
      P0r[k] = wf[OFF_P0 + j*16 + k];
    }
    const float invc0 = wf[OFF_FS+3];
    float mu0j = mu0[j];
    float q0  = wf[OFF_Q + (size_t)n*131072 + j];
    float xx0 = wf[OFF_XX + (size_t)n*T_TOT];
    float h0; MV16(Sr, mu0j, h0);
    float u0 = q0 - h0;
    float w0; MV16(P0r, u0, w0);
    float loc = fmaf(-2.f*q0, mu0j, fmaf(mu0j, h0, -(u0*w0*invc0)));
    RED16(loc);
    if (j == 0) wf[OFF_FQ + n] = (xx0 + loc)*invc0;
    float muf = fmaf(w0, invc0, mu0j);
    float en; MV16(Ar, muf, en);
    wf[OFF_EN0 + n*16 + j] = en;
    return;
  }

  const int chunk = blockIdx.x;
  float Fr[16], Kr[16];
  #pragma unroll
  for (int k = 0; k < 16; ++k) {
    Fr[k] = wf[OFF_F  + j*16 + k];
    Kr[k] = wf[OFF_KQ + j*16 + k];
  }
  const int t0 = 1 + CHLEN*chunk;
  const int ns = (CHLEN < (T_TOT-1) - t0 + 1) ? CHLEN : ((T_TOT-1) - t0 + 1);
  const float* qp = wf + OFF_Q + (size_t)n*131072 + (size_t)t0*16 + j;
  float mud = 0.f;
  #pragma unroll 1
  for (int s = 0; s < ns; ++s) {
    float qj = qp[0]; qp += 16;
    float g; MV16(Kr, qj, g);
    float fm; MV16(Fr, mud, fm);
    mud = fm + g;
  }
  wf[OFF_VC + chunk*512 + n*16 + j] = mud;
}

// =====================================================================
// Pass C: entry reconstruction (parallel) + replay + LL quadratics.
// en_c = vc_{c-1} + M64*(x2 + M64*x3); exact for c<=2, O(M64^3) after.
// =====================================================================
__global__ __launch_bounds__(256) void k_passC(const float* __restrict__ A)
{
  const int tid = threadIdx.x; const int j = tid & 15;
  const int n = blockIdx.y*16 + (tid >> 4);
  const int chunk = blockIdx.x;
  float* __restrict__ wf = g_wf;
  float Ar[16], Sr[16], Pr[16], Mr[16];
  #pragma unroll
  for (int k = 0; k < 16; ++k) {
    Ar[k] = A[j*16+k];
    Sr[k] = wf[OFF_S   + j*16 + k];
    Pr[k] = wf[OFF_PSS + j*16 + k];
    Mr[k] = wf[OFF_M64 + j*16 + k];
  }
  const float invc = wf[OFF_FS+2];

  float mud;
  if (chunk == 0) {
    mud = wf[OFF_EN0 + n*16 + j];
  } else {
    float v1 = wf[OFF_VC + (chunk-1)*512 + n*16 + j];
    float x2 = (chunk == 1) ? wf[OFF_EN0 + n*16 + j]
                            : wf[OFF_VC + (chunk-2)*512 + n*16 + j];
    float x3 = (chunk == 2) ? wf[OFF_EN0 + n*16 + j]
             : (chunk >= 3) ? wf[OFF_VC + (chunk-3)*512 + n*16 + j] : 0.f;
    float m3; MV16(Mr, x3, m3);
    float y = x2 + m3;
    float m2; MV16(Mr, y, m2);
    mud = v1 + m2;
  }

  const int t0 = 1 + CHLEN*chunk;
  const int ns = (CHLEN < (T_TOT-1) - t0 + 1) ? CHLEN : ((T_TOT-1) - t0 + 1);
  const float* qp  = wf + OFF_Q  + (size_t)n*131072 + (size_t)t0*16 + j;
  const float* xxp = wf + OFF_XX + (size_t)n*T_TOT + t0;
  float qacc = 0.f;
  #pragma unroll 1
  for (int s = 0; s < ns; ++s) {
    float qj = qp[0]; qp += 16;
    float xxv = xxp[0]; xxp += 1;
    float h; MV16(Sr, mud, h);
    float u = qj - h;
    float w; MV16(Pr, u, w);
    float loc = fmaf(-2.f*qj, mud, fmaf(mud, h, -(u*w*invc)));
    RED16(loc);
    qacc = fmaf(xxv + loc, invc, qacc);
    float tmp = fmaf(w, invc, mud);
    MV16(Ar, tmp, mud);
  }
  if (j == 0) wf[OFF_QS + chunk*32 + n] = qacc;
}

// =====================================================================
// Final assembly.
// =====================================================================
__global__ __launch_bounds__(64) void k_final(float* __restrict__ out)
{
  const int n = threadIdx.x;
  if (n >= NTR) return;
  const float* wf = g_wf;
  const double* dsc = (const double*)wf;
  double acc = (double)wf[OFF_FQ + n];
  #pragma unroll 8
  for (int i = 0; i < NCHUNK; ++i) acc += (double)wf[OFF_QS + i*32 + n];
  const double LOG2PI = 1.8378770664093453;
  double ll = -32.0*LOG2PI*(double)T_TOT - dsc[0] - dsc[1] - 0.5*acc;
  out[n] = (float)ll;
}

extern "C" void kernel_launch(void* const* d_in, const int* in_sizes, int n_in,
                              void* d_out, int out_size, void* d_ws, size_t ws_size,
                              hipStream_t stream)
{
  (void)in_sizes; (void)n_in; (void)out_size; (void)d_ws; (void)ws_size;
  const float* v   = (const float*)d_in[0];
  const float* A   = (const float*)d_in[1];
  const float* B   = (const float*)d_in[2];
  const float* W   = (const float*)d_in[3];
  const float* mu0 = (const float*)d_in[4];
  const float* S0h = (const float*)d_in[5];
  const float* lsv = (const float*)d_in[6];
  float* out = (float*)d_out;

  k_front<<<1 + NTR*16, 256, 0, stream>>>(v, A, B, W, S0h, lsv);
  k_passA<<<dim3(NCHUNK+1,2), 256, 0, stream>>>(A, mu0);
  k_passC<<<dim3(NCHUNK,2), 256, 0, stream>>>(A);
  k_final<<<1, 64, 0, stream>>>(out);
}

// Round 6
// 182.677 us; speedup vs baseline: 5.5802x; 1.1974x over previous
//
#include <hip/hip_runtime.h>
#include <math.h>

// Kalman forward LL: Woodbury 16-dim reduction + steady-state Riccati
// computed entirely in registers (single wave, ds_bpermute cross-lane),
// + fine-grained chunked parallel scan (CHLEN=16, 512 chunks).

#define T_TOT 8192
#define NTR   32
#define VD    64
#define NCHUNK 512
#define CHLEN  16
#define NI     12     // exact Riccati iterations, then steady state

// ---- workspace layout (floats; doubles occupy wf[0..7]) ----
#define OFF_FS    8
#define OFF_S     16
#define OFF_P0    272
#define OFF_PSS   528
#define OFF_F     784
#define OFF_M16   1040
#define OFF_KQ    1296
#define OFF_EN0   1552                     // 512
#define OFF_FQ    2064                     // 32
#define OFF_VC    2096                     // NCHUNK*512
#define OFF_QS    (OFF_VC + NCHUNK*512)    // NCHUNK*32
#define OFF_Q     (OFF_QS + NCHUNK*32)     // [n][t][16]
#define OFF_XX    (OFF_Q + T_TOT*512)      // [n][t]
#define WS_FLOATS (OFF_XX + T_TOT*32 + 64) // +64 pad for chunk-511 OOB-safe reads

__device__ float g_wf[WS_FLOATS];

// ---- 16-lane-group swizzle helpers (pass kernels) ----
#define SWZ(x, imm) __int_as_float(__builtin_amdgcn_ds_swizzle(__float_as_int(x), (imm)))

#define MV16(row, vv, out) do { \
  float b0_=SWZ(vv,0x010), b1_=SWZ(vv,0x030), b2_=SWZ(vv,0x050), b3_=SWZ(vv,0x070); \
  float b4_=SWZ(vv,0x090), b5_=SWZ(vv,0x0B0), b6_=SWZ(vv,0x0D0), b7_=SWZ(vv,0x0F0); \
  float b8_=SWZ(vv,0x110), b9_=SWZ(vv,0x130), b10_=SWZ(vv,0x150), b11_=SWZ(vv,0x170); \
  float b12_=SWZ(vv,0x190), b13_=SWZ(vv,0x1B0), b14_=SWZ(vv,0x1D0), b15_=SWZ(vv,0x1F0); \
  float s0_=fmaf((row)[0],b0_,fmaf((row)[1],b1_,fmaf((row)[2],b2_,(row)[3]*b3_))); \
  float s1_=fmaf((row)[4],b4_,fmaf((row)[5],b5_,fmaf((row)[6],b6_,(row)[7]*b7_))); \
  float s2_=fmaf((row)[8],b8_,fmaf((row)[9],b9_,fmaf((row)[10],b10_,(row)[11]*b11_))); \
  float s3_=fmaf((row)[12],b12_,fmaf((row)[13],b13_,fmaf((row)[14],b14_,(row)[15]*b15_))); \
  (out)=(s0_+s1_)+(s2_+s3_); \
} while(0)

#define RED16(x) do { x+=SWZ(x,0x041F); x+=SWZ(x,0x081F); x+=SWZ(x,0x101F); x+=SWZ(x,0x201F); } while(0)

// =====================================================================
// Register-resident 16x16 primitives (single wave of 64 lanes).
// Lane l = 4*i + g holds cols 4g..4g+3 of row i in 4 VGPRs.
// =====================================================================
__device__ __forceinline__ void mm_reg(float* C, const float* Aa, const float* Bb, int lane)
{
  const int rowbase = lane & 0x3C;
  const int g = lane & 3;
  #pragma unroll
  for (int j = 0; j < 4; ++j) C[j] = 0.f;
  #pragma unroll
  for (int k = 0; k < 16; ++k) {
    float a = __shfl(Aa[k & 3], rowbase | (k >> 2), 64);
    #pragma unroll
    for (int j = 0; j < 4; ++j) {
      float b = __shfl(Bb[j], 4*k + g, 64);
      C[j] = fmaf(a, b, C[j]);
    }
  }
}

__device__ __forceinline__ void mmbt_reg(float* C, const float* Aa, const float* Bb, int lane)
{
  const int rowbase = lane & 0x3C;
  const int g = lane & 3;
  #pragma unroll
  for (int j = 0; j < 4; ++j) C[j] = 0.f;
  #pragma unroll
  for (int k = 0; k < 16; ++k) {
    float a = __shfl(Aa[k & 3], rowbase | (k >> 2), 64);
    #pragma unroll
    for (int j = 0; j < 4; ++j) {
      float bt = __shfl(Bb[k & 3], 16*g + 4*j + (k >> 2), 64);
      C[j] = fmaf(a, bt, C[j]);
    }
  }
}

// Augmented GJ in registers: M -> diag, R -> M^{-1} R. Returns log|det M|.
__device__ __forceinline__ float gj_reg(float* M, float* R, int lane)
{
  const int i = lane >> 2;
  const int rowbase = lane & 0x3C;
  const int g = lane & 3;
  float ld = 0.f;
  #pragma unroll
  for (int k = 0; k < 16; ++k) {
    float p = __shfl(M[k & 3], 4*k + (k >> 2), 64);
    ld += __logf(fabsf(p));
    float r = 1.f / p;
    float f = __shfl(M[k & 3], rowbase | (k >> 2), 64) * r;
    float t = (i != k) ? f : 0.f;
    #pragma unroll
    for (int j = 0; j < 4; ++j) {
      float mk = __shfl(M[j], 4*k + g, 64);
      float rk = __shfl(R[j], 4*k + g, 64);
      M[j] = fmaf(-t, mk, M[j]);
      R[j] = fmaf(-t, rk, R[j]);
    }
  }
  int e = i & 3;
  float dm = (e & 2) ? ((e & 1) ? M[3] : M[2]) : ((e & 1) ? M[1] : M[0]);
  float d = __shfl(dm, 4*i + (i >> 2), 64);
  float rd = 1.f / d;
  #pragma unroll
  for (int j = 0; j < 4; ++j) R[j] *= rd;
  return ld;
}

// =====================================================================
// Fused front: block 0 = setup(256 thr) + register Riccati (wave 0);
// blocks >= 1 = q/xx pass.
// =====================================================================
__global__ __launch_bounds__(256) void k_front(const float* __restrict__ v,
                                               const float* __restrict__ A,
                                               const float* __restrict__ B,
                                               const float* __restrict__ W,
                                               const float* __restrict__ S0h,
                                               const float* __restrict__ lsv)
{
  const int tid = threadIdx.x;
  float* __restrict__ wf = g_wf;

  if (blockIdx.x != 0) {
    __shared__ float Wl[VD][16];
    for (int e = tid; e < VD*16; e += 256) Wl[e>>4][e&15] = W[e];
    __syncthreads();
    const int bid = blockIdx.x - 1;
    const int n = bid >> 4;
    const int t0 = (bid & 15)*512 + tid*2;
    const float* vp = v + (size_t)n*VD*T_TOT + t0;
    float a0[16], a1[16];
    #pragma unroll
    for (int k = 0; k < 16; ++k) { a0[k] = 0.f; a1[k] = 0.f; }
    float s20 = 0.f, s21 = 0.f;
    #pragma unroll 4
    for (int i2 = 0; i2 < VD; ++i2) {
      float2 x = *(const float2*)&vp[(size_t)i2*T_TOT];
      s20 = fmaf(x.x, x.x, s20); s21 = fmaf(x.y, x.y, s21);
      const float4* wr = (const float4*)&Wl[i2][0];
      float4 w0 = wr[0], w1 = wr[1], w2 = wr[2], w3 = wr[3];
      a0[0]=fmaf(x.x,w0.x,a0[0]);  a1[0]=fmaf(x.y,w0.x,a1[0]);
      a0[1]=fmaf(x.x,w0.y,a0[1]);  a1[1]=fmaf(x.y,w0.y,a1[1]);
      a0[2]=fmaf(x.x,w0.z,a0[2]);  a1[2]=fmaf(x.y,w0.z,a1[2]);
      a0[3]=fmaf(x.x,w0.w,a0[3]);  a1[3]=fmaf(x.y,w0.w,a1[3]);
      a0[4]=fmaf(x.x,w1.x,a0[4]);  a1[4]=fmaf(x.y,w1.x,a1[4]);
      a0[5]=fmaf(x.x,w1.y,a0[5]);  a1[5]=fmaf(x.y,w1.y,a1[5]);
      a0[6]=fmaf(x.x,w1.z,a0[6]);  a1[6]=fmaf(x.y,w1.z,a1[6]);
      a0[7]=fmaf(x.x,w1.w,a0[7]);  a1[7]=fmaf(x.y,w1.w,a1[7]);
      a0[8]=fmaf(x.x,w2.x,a0[8]);  a1[8]=fmaf(x.y,w2.x,a1[8]);
      a0[9]=fmaf(x.x,w2.y,a0[9]);  a1[9]=fmaf(x.y,w2.y,a1[9]);
      a0[10]=fmaf(x.x,w2.z,a0[10]); a1[10]=fmaf(x.y,w2.z,a1[10]);
      a0[11]=fmaf(x.x,w2.w,a0[11]); a1[11]=fmaf(x.y,w2.w,a1[11]);
      a0[12]=fmaf(x.x,w3.x,a0[12]); a1[12]=fmaf(x.y,w3.x,a1[12]);
      a0[13]=fmaf(x.x,w3.y,a0[13]); a1[13]=fmaf(x.y,w3.y,a1[13]);
      a0[14]=fmaf(x.x,w3.z,a0[14]); a1[14]=fmaf(x.y,w3.z,a1[14]);
      a0[15]=fmaf(x.x,w3.w,a0[15]); a1[15]=fmaf(x.y,w3.w,a1[15]);
    }
    float4* q0 = (float4*)(wf + OFF_Q + (size_t)n*131072 + (size_t)t0*16);
    q0[0] = make_float4(a0[0],a0[1],a0[2],a0[3]);
    q0[1] = make_float4(a0[4],a0[5],a0[6],a0[7]);
    q0[2] = make_float4(a0[8],a0[9],a0[10],a0[11]);
    q0[3] = make_float4(a0[12],a0[13],a0[14],a0[15]);
    q0[4] = make_float4(a1[0],a1[1],a1[2],a1[3]);
    q0[5] = make_float4(a1[4],a1[5],a1[6],a1[7]);
    q0[6] = make_float4(a1[8],a1[9],a1[10],a1[11]);
    q0[7] = make_float4(a1[12],a1[13],a1[14],a1[15]);
    wf[OFF_XX + (size_t)n*T_TOT + t0]     = s20;
    wf[OFF_XX + (size_t)n*T_TOT + t0 + 1] = s21;
    return;
  }

  // ---------------- block 0: setup in LDS (256 thr) ----------------
  __shared__ float Wl[VD][16];
  __shared__ float Al[16][16], Sm_l[16][16], Qm_l[16][16], S0_l[16][16];
  const int ri = tid >> 4, ci = tid & 15;
  for (int e = tid; e < VD*16; e += 256) Wl[e>>4][e&15] = W[e];
  Al[ri][ci] = A[tid];
  __syncthreads();
  {
    float s = 0.f;
    for (int r = 0; r < VD; ++r) s = fmaf(Wl[r][ri], Wl[r][ci], s);
    Sm_l[ri][ci] = s;
    int m = ri < ci ? ri : ci;
    float q = (ri==ci)?1e-6f:0.f, g0 = (ri==ci)?1e-6f:0.f;
    for (int r = 0; r <= m; ++r) {
      q  = fmaf(B[ri*16+r],   B[ci*16+r],   q);
      g0 = fmaf(S0h[ri*16+r], S0h[ci*16+r], g0);
    }
    Qm_l[ri][ci] = q;
    S0_l[ri][ci] = g0;
  }
  __syncthreads();
  if (tid >= 64) return;

  // ---------------- wave 0: register Riccati ----------------
  const int lane = tid;
  const int i = lane >> 2, g = lane & 3;
  float al[4], sm[4], qm[4], s0[4], scl[4], scl0[4], dmask[4];
  {
    float4 t;
    t = *(const float4*)&Al[i][4*g];   al[0]=t.x; al[1]=t.y; al[2]=t.z; al[3]=t.w;
    t = *(const float4*)&Sm_l[i][4*g]; sm[0]=t.x; sm[1]=t.y; sm[2]=t.z; sm[3]=t.w;
    t = *(const float4*)&Qm_l[i][4*g]; qm[0]=t.x; qm[1]=t.y; qm[2]=t.z; qm[3]=t.w;
    t = *(const float4*)&S0_l[i][4*g]; s0[0]=t.x; s0[1]=t.y; s0[2]=t.z; s0[3]=t.w;
  }
  #pragma unroll
  for (int j = 0; j < 4; ++j) dmask[j] = (4*g + j == i) ? 1.f : 0.f;

  float ev = expf(lsv[0]); float var = ev*ev;
  float c0v = var + 1e-6f, cv = var + 2e-6f;
  float invc0 = 1.f/c0v, invc = 1.f/cv;
  float logc = __logf(cv);
  #pragma unroll
  for (int j = 0; j < 4; ++j) { scl0[j] = sm[j]*invc0; scl[j] = sm[j]*invc; }

  // t=0: G0 = I + Sigma0*(S/c0); P0 = G0^-1 Sigma0
  float gm[4];
  mm_reg(gm, s0, scl0, lane);
  #pragma unroll
  for (int j = 0; j < 4; ++j) gm[j] += dmask[j];
  float ld0 = gj_reg(gm, s0, lane);            // s0 := P0
  float ldet_first = 0.5f*(64.f*__logf(c0v) + ld0);
  {
    float4* w4;
    w4 = (float4*)(wf + OFF_P0 + i*16 + 4*g); *w4 = make_float4(s0[0],s0[1],s0[2],s0[3]);
    w4 = (float4*)(wf + OFF_S  + i*16 + 4*g); *w4 = make_float4(sm[0],sm[1],sm[2],sm[3]);
  }

  float p[4];
  #pragma unroll
  for (int j = 0; j < 4; ++j) p[j] = s0[j];

  double dacc = 0.0; float ld_t = 0.f;
  float t1[4], sd[4];
  #pragma unroll 1
  for (int t = 0; t < NI; ++t) {
    mm_reg(t1, al, p, lane);                   // A P
    mmbt_reg(sd, t1, al, lane);                // A P A^T
    #pragma unroll
    for (int j = 0; j < 4; ++j) sd[j] += qm[j];        // Sd
    mm_reg(gm, sd, scl, lane);                 // Sd S/c
    #pragma unroll
    for (int j = 0; j < 4; ++j) gm[j] += dmask[j];     // G
    float ldG = gj_reg(gm, sd, lane);          // sd := P_new
    #pragma unroll
    for (int j = 0; j < 4; ++j) p[j] = sd[j];
    ld_t = 0.5f*(64.f*logc + ldG);
    dacc += (double)ld_t;
  }
  double ldet_total = dacc + (double)(T_TOT-1-NI)*(double)ld_t;

  // steady state: Kq = A P/c ; F = A - Kq S ; M16 = F^16
  float kq[4], fm_[4], tB[4];
  mm_reg(t1, al, p, lane);
  #pragma unroll
  for (int j = 0; j < 4; ++j) kq[j] = t1[j]*invc;
  mm_reg(tB, kq, sm, lane);
  #pragma unroll
  for (int j = 0; j < 4; ++j) fm_[j] = al[j] - tB[j];
  {
    float4* w4;
    w4 = (float4*)(wf + OFF_PSS + i*16 + 4*g); *w4 = make_float4(p[0],p[1],p[2],p[3]);
    w4 = (float4*)(wf + OFF_F   + i*16 + 4*g); *w4 = make_float4(fm_[0],fm_[1],fm_[2],fm_[3]);
    w4 = (float4*)(wf + OFF_KQ  + i*16 + 4*g); *w4 = make_float4(kq[0],kq[1],kq[2],kq[3]);
  }
  mm_reg(t1, fm_, fm_, lane);   // F^2
  mm_reg(tB, t1, t1, lane);     // F^4
  mm_reg(t1, tB, tB, lane);     // F^8
  mm_reg(tB, t1, t1, lane);     // F^16
  {
    float4* w4 = (float4*)(wf + OFF_M16 + i*16 + 4*g);
    *w4 = make_float4(tB[0],tB[1],tB[2],tB[3]);
  }
  if (lane == 0) {
    double* d = (double*)wf;
    d[0] = (double)ldet_first;
    d[1] = ldet_total;
    wf[OFF_FS+0] = c0v; wf[OFF_FS+1] = cv; wf[OFF_FS+2] = invc; wf[OFF_FS+3] = invc0;
  }
}

// =====================================================================
// Pass A: chunk-local offsets (F-form) + t0-term block (x == NCHUNK).
// =====================================================================
__global__ __launch_bounds__(256) void k_passA(const float* __restrict__ A,
                                               const float* __restrict__ mu0)
{
  const int tid = threadIdx.x; const int j = tid & 15;
  const int n = blockIdx.y*16 + (tid >> 4);
  float* __restrict__ wf = g_wf;

  if (blockIdx.x == NCHUNK) {
    float Ar[16], Sr[16], P0r[16];
    #pragma unroll
    for (int k = 0; k < 16; ++k) {
      Ar[k]  = A[j*16+k];
      Sr[k]  = wf[OFF_S  + j*16 + k];
      P0r[k] = wf[OFF_P0 + j*16 + k];
    }
    const float invc0 = wf[OFF_FS+3];
    float mu0j = mu0[j];
    float q0  = wf[OFF_Q + (size_t)n*131072 + j];
    float xx0 = wf[OFF_XX + (size_t)n*T_TOT];
    float h0; MV16(Sr, mu0j, h0);
    float u0 = q0 - h0;
    float w0; MV16(P0r, u0, w0);
    float loc = fmaf(-2.f*q0, mu0j, fmaf(mu0j, h0, -(u0*w0*invc0)));
    RED16(loc);
    if (j == 0) wf[OFF_FQ + n] = (xx0 + loc)*invc0;
    float muf = fmaf(w0, invc0, mu0j);
    float en; MV16(Ar, muf, en);
    wf[OFF_EN0 + n*16 + j] = en;
    return;
  }

  const int chunk = blockIdx.x;
  float Fr[16], Kr[16];
  #pragma unroll
  for (int k = 0; k < 16; ++k) {
    Fr[k] = wf[OFF_F  + j*16 + k];
    Kr[k] = wf[OFF_KQ + j*16 + k];
  }
  const int t0 = 1 + CHLEN*chunk;
  const float* qp = wf + OFF_Q + (size_t)n*131072 + (size_t)t0*16 + j;
  float mud = 0.f;
  #pragma unroll
  for (int s = 0; s < CHLEN; ++s) {
    float qj = qp[s*16];
    float g; MV16(Kr, qj, g);
    float fm; MV16(Fr, mud, fm);
    mud = fm + g;
  }
  wf[OFF_VC + chunk*512 + n*16 + j] = mud;
}

// =====================================================================
// Pass C: parallel entry reconstruction + replay + LL quadratics.
// en_c = vc_{c-1} + M16*(x2 + M16*x3); exact for c<=2, O(F^48) after.
// =====================================================================
__global__ __launch_bounds__(256) void k_passC(const float* __restrict__ A)
{
  const int tid = threadIdx.x; const int j = tid & 15;
  const int n = blockIdx.y*16 + (tid >> 4);
  const int chunk = blockIdx.x;
  float* __restrict__ wf = g_wf;
  float Ar[16], Sr[16], Pr[16], Mr[16];
  #pragma unroll
  for (int k = 0; k < 16; ++k) {
    Ar[k] = A[j*16+k];
    Sr[k] = wf[OFF_S   + j*16 + k];
    Pr[k] = wf[OFF_PSS + j*16 + k];
    Mr[k] = wf[OFF_M16 + j*16 + k];
  }
  const float invc = wf[OFF_FS+2];

  float mud;
  if (chunk == 0) {
    mud = wf[OFF_EN0 + n*16 + j];
  } else {
    float v1 = wf[OFF_VC + (chunk-1)*512 + n*16 + j];
    float x2 = (chunk == 1) ? wf[OFF_EN0 + n*16 + j]
                            : wf[OFF_VC + (chunk-2)*512 + n*16 + j];
    float x3 = (chunk == 2) ? wf[OFF_EN0 + n*16 + j]
             : (chunk >= 3) ? wf[OFF_VC + (chunk-3)*512 + n*16 + j] : 0.f;
    float m3; MV16(Mr, x3, m3);
    float y = x2 + m3;
    float m2; MV16(Mr, y, m2);
    mud = v1 + m2;
  }

  const int t0 = 1 + CHLEN*chunk;
  const int ns = (CHLEN < (T_TOT-1) - t0 + 1) ? CHLEN : ((T_TOT-1) - t0 + 1);
  const float* qp  = wf + OFF_Q  + (size_t)n*131072 + (size_t)t0*16 + j;
  const float* xxp = wf + OFF_XX + (size_t)n*T_TOT + t0;
  float qacc = 0.f;
  #pragma unroll 4
  for (int s = 0; s < CHLEN; ++s) {
    float qj = qp[s*16];
    float xxv = xxp[s];
    float h; MV16(Sr, mud, h);
    float u = qj - h;
    float w; MV16(Pr, u, w);
    float loc = fmaf(-2.f*qj, mud, fmaf(mud, h, -(u*w*invc)));
    RED16(loc);
    if (s < ns) qacc = fmaf(xxv + loc, invc, qacc);
    float tmp = fmaf(w, invc, mud);
    MV16(Ar, tmp, mud);
  }
  if (j == 0) wf[OFF_QS + chunk*32 + n] = qacc;
}

// =====================================================================
// Final assembly: 8 slices x 32 trials, LDS reduce.
// =====================================================================
__global__ __launch_bounds__(256) void k_final(float* __restrict__ out)
{
  const int tid = threadIdx.x;
  const int slice = tid >> 5, n = tid & 31;
  const float* wf = g_wf;
  __shared__ double red[8][32];
  double acc = 0.0;
  #pragma unroll 8
  for (int k = 0; k < NCHUNK/8; ++k)
    acc += (double)wf[OFF_QS + (slice*(NCHUNK/8) + k)*32 + n];
  red[slice][n] = acc;
  __syncthreads();
  if (tid < 32) {
    const double* dsc = (const double*)wf;
    double a = (double)wf[OFF_FQ + tid];
    #pragma unroll
    for (int s = 0; s < 8; ++s) a += red[s][tid];
    const double LOG2PI = 1.8378770664093453;
    double ll = -32.0*LOG2PI*(double)T_TOT - dsc[0] - dsc[1] - 0.5*a;
    out[tid] = (float)ll;
  }
}

extern "C" void kernel_launch(void* const* d_in, const int* in_sizes, int n_in,
                              void* d_out, int out_size, void* d_ws, size_t ws_size,
                              hipStream_t stream)
{
  (void)in_sizes; (void)n_in; (void)out_size; (void)d_ws; (void)ws_size;
  const float* v   = (const float*)d_in[0];
  const float* A   = (const float*)d_in[1];
  const float* B   = (const float*)d_in[2];
  const float* W   = (const float*)d_in[3];
  const float* mu0 = (const float*)d_in[4];
  const float* S0h = (const float*)d_in[5];
  const float* lsv = (const float*)d_in[6];
  float* out = (float*)d_out;

  k_front<<<1 + NTR*16, 256, 0, stream>>>(v, A, B, W, S0h, lsv);
  k_passA<<<dim3(NCHUNK+1,2), 256, 0, stream>>>(A, mu0);
  k_passC<<<dim3(NCHUNK,2), 256, 0, stream>>>(A);
  k_final<<<1, 256, 0, stream>>>(out);
}

// Round 7
// 165.906 us; speedup vs baseline: 6.1443x; 1.1011x over previous
//
#include <hip/hip_runtime.h>
#include <math.h>

// Kalman forward LL: Woodbury 16-dim reduction + steady-state Riccati in
// registers (single wave; DPP quad_perm + readlane + ds_bpermute), +
// fine-grained chunked parallel scan (CHLEN=16) with F-form recursions.

#define T_TOT 8192
#define NTR   32
#define VD    64
#define NCHUNK 512
#define CHLEN  16
#define NI     8      // exact Riccati iterations, then steady state

// ---- workspace layout (floats; doubles occupy wf[0..7]) ----
#define OFF_FS    8
#define OFF_S     16
#define OFF_P0    272
#define OFF_PSS   528
#define OFF_F     784
#define OFF_M16   1040
#define OFF_KQ    1296
#define OFF_EN0   1552                     // 512
#define OFF_FQ    2064                     // 32
#define OFF_VC    2096                     // NCHUNK*512
#define OFF_QS    (OFF_VC + NCHUNK*512)    // NCHUNK*32
#define OFF_Q     (OFF_QS + NCHUNK*32)     // [n][t][16]
#define OFF_XX    (OFF_Q + T_TOT*512)      // [n][t]
#define WS_FLOATS (OFF_XX + T_TOT*32 + 64) // +64 pad for chunk-511 OOB-safe reads

__device__ float g_wf[WS_FLOATS];

// ---- 16-lane-group swizzle helpers (pass kernels) ----
#define SWZ(x, imm) __int_as_float(__builtin_amdgcn_ds_swizzle(__float_as_int(x), (imm)))

#define MV16(row, vv, out) do { \
  float b0_=SWZ(vv,0x010), b1_=SWZ(vv,0x030), b2_=SWZ(vv,0x050), b3_=SWZ(vv,0x070); \
  float b4_=SWZ(vv,0x090), b5_=SWZ(vv,0x0B0), b6_=SWZ(vv,0x0D0), b7_=SWZ(vv,0x0F0); \
  float b8_=SWZ(vv,0x110), b9_=SWZ(vv,0x130), b10_=SWZ(vv,0x150), b11_=SWZ(vv,0x170); \
  float b12_=SWZ(vv,0x190), b13_=SWZ(vv,0x1B0), b14_=SWZ(vv,0x1D0), b15_=SWZ(vv,0x1F0); \
  float s0_=fmaf((row)[0],b0_,fmaf((row)[1],b1_,fmaf((row)[2],b2_,(row)[3]*b3_))); \
  float s1_=fmaf((row)[4],b4_,fmaf((row)[5],b5_,fmaf((row)[6],b6_,(row)[7]*b7_))); \
  float s2_=fmaf((row)[8],b8_,fmaf((row)[9],b9_,fmaf((row)[10],b10_,(row)[11]*b11_))); \
  float s3_=fmaf((row)[12],b12_,fmaf((row)[13],b13_,fmaf((row)[14],b14_,(row)[15]*b15_))); \
  (out)=(s0_+s1_)+(s2_+s3_); \
} while(0)

#define RED16(x) do { x+=SWZ(x,0x041F); x+=SWZ(x,0x081F); x+=SWZ(x,0x101F); x+=SWZ(x,0x201F); } while(0)

// ---- single-wave 16x16 register primitives ----
// Lane l = 4*i + g holds M[i][4g..4g+3] in 4 VGPRs.
#define DPPQ(x, sel) __int_as_float(__builtin_amdgcn_update_dpp( \
    0, __float_as_int(x), (sel)*0x55, 0xF, 0xF, true))
#define RDLANE(x, l) __int_as_float(__builtin_amdgcn_readlane(__float_as_int(x), (l)))
__device__ __forceinline__ float bperm4(int addr, float v) {
  return __int_as_float(__builtin_amdgcn_ds_bpermute(addr, __float_as_int(v)));
}

// C = Aa * Bb
__device__ __forceinline__ void mmF(float* C, const float* Aa, const float* Bb, int bA)
{
  C[0]=0.f; C[1]=0.f; C[2]=0.f; C[3]=0.f;
#define MMK(k) { float a_ = DPPQ(Aa[(k)&3], ((k)>>2)); int ad_ = bA + 16*(k); \
    C[0]=fmaf(a_, bperm4(ad_, Bb[0]), C[0]); C[1]=fmaf(a_, bperm4(ad_, Bb[1]), C[1]); \
    C[2]=fmaf(a_, bperm4(ad_, Bb[2]), C[2]); C[3]=fmaf(a_, bperm4(ad_, Bb[3]), C[3]); }
  MMK(0) MMK(1) MMK(2) MMK(3) MMK(4) MMK(5) MMK(6) MMK(7)
  MMK(8) MMK(9) MMK(10) MMK(11) MMK(12) MMK(13) MMK(14) MMK(15)
#undef MMK
}

// C = Aa * Bb^T
__device__ __forceinline__ void mmbtF(float* C, const float* Aa, const float* Bb, int bT)
{
  C[0]=0.f; C[1]=0.f; C[2]=0.f; C[3]=0.f;
#define MBK(k) { float a_ = DPPQ(Aa[(k)&3], ((k)>>2)); \
    C[0]=fmaf(a_, bperm4(bT +  0 + 4*((k)>>2), Bb[(k)&3]), C[0]); \
    C[1]=fmaf(a_, bperm4(bT + 16 + 4*((k)>>2), Bb[(k)&3]), C[1]); \
    C[2]=fmaf(a_, bperm4(bT + 32 + 4*((k)>>2), Bb[(k)&3]), C[2]); \
    C[3]=fmaf(a_, bperm4(bT + 48 + 4*((k)>>2), Bb[(k)&3]), C[3]); }
  MBK(0) MBK(1) MBK(2) MBK(3) MBK(4) MBK(5) MBK(6) MBK(7)
  MBK(8) MBK(9) MBK(10) MBK(11) MBK(12) MBK(13) MBK(14) MBK(15)
#undef MBK
}

// Augmented GJ: M -> diag, R -> M^{-1} R (normalized); dp *= det(M).
__device__ __forceinline__ void gjF(float* M, float* R, int bA, int i, double& dp)
{
#define GJK(k) { int ad_ = bA + 16*(k); \
    float mk0_=bperm4(ad_,M[0]), mk1_=bperm4(ad_,M[1]), mk2_=bperm4(ad_,M[2]), mk3_=bperm4(ad_,M[3]); \
    float rk0_=bperm4(ad_,R[0]), rk1_=bperm4(ad_,R[1]), rk2_=bperm4(ad_,R[2]), rk3_=bperm4(ad_,R[3]); \
    float p_ = RDLANE(M[(k)&3], 4*(k)+((k)>>2)); \
    float f_ = DPPQ(M[(k)&3], ((k)>>2)); \
    float t_ = (i != (k)) ? f_*(1.f/p_) : 0.f; \
    dp *= (double)p_; \
    M[0]=fmaf(-t_,mk0_,M[0]); M[1]=fmaf(-t_,mk1_,M[1]); \
    M[2]=fmaf(-t_,mk2_,M[2]); M[3]=fmaf(-t_,mk3_,M[3]); \
    R[0]=fmaf(-t_,rk0_,R[0]); R[1]=fmaf(-t_,rk1_,R[1]); \
    R[2]=fmaf(-t_,rk2_,R[2]); R[3]=fmaf(-t_,rk3_,R[3]); }
  GJK(0) GJK(1) GJK(2) GJK(3) GJK(4) GJK(5) GJK(6) GJK(7)
  GJK(8) GJK(9) GJK(10) GJK(11) GJK(12) GJK(13) GJK(14) GJK(15)
#undef GJK
  float dm = (i & 2) ? ((i & 1) ? M[3] : M[2]) : ((i & 1) ? M[1] : M[0]);
  float d = bperm4((4*i + (i>>2))*4, dm);
  float rd = 1.f/d;
  R[0]*=rd; R[1]*=rd; R[2]*=rd; R[3]*=rd;
}

// =====================================================================
// Fused front: block 0 = setup(256 thr) + register Riccati (wave 0);
// blocks >= 1 = q/xx pass.
// =====================================================================
__global__ __launch_bounds__(256) void k_front(const float* __restrict__ v,
                                               const float* __restrict__ A,
                                               const float* __restrict__ B,
                                               const float* __restrict__ W,
                                               const float* __restrict__ S0h,
                                               const float* __restrict__ lsv)
{
  const int tid = threadIdx.x;
  float* __restrict__ wf = g_wf;

  if (blockIdx.x != 0) {
    __shared__ float Wl[VD][16];
    for (int e = tid; e < VD*16; e += 256) Wl[e>>4][e&15] = W[e];
    __syncthreads();
    const int bid = blockIdx.x - 1;
    const int n = bid >> 4;
    const int t0 = (bid & 15)*512 + tid*2;
    const float* vp = v + (size_t)n*VD*T_TOT + t0;
    float a0[16], a1[16];
    #pragma unroll
    for (int k = 0; k < 16; ++k) { a0[k] = 0.f; a1[k] = 0.f; }
    float s20 = 0.f, s21 = 0.f;
    #pragma unroll 4
    for (int i2 = 0; i2 < VD; ++i2) {
      float2 x = *(const float2*)&vp[(size_t)i2*T_TOT];
      s20 = fmaf(x.x, x.x, s20); s21 = fmaf(x.y, x.y, s21);
      const float4* wr = (const float4*)&Wl[i2][0];
      float4 w0 = wr[0], w1 = wr[1], w2 = wr[2], w3 = wr[3];
      a0[0]=fmaf(x.x,w0.x,a0[0]);  a1[0]=fmaf(x.y,w0.x,a1[0]);
      a0[1]=fmaf(x.x,w0.y,a0[1]);  a1[1]=fmaf(x.y,w0.y,a1[1]);
      a0[2]=fmaf(x.x,w0.z,a0[2]);  a1[2]=fmaf(x.y,w0.z,a1[2]);
      a0[3]=fmaf(x.x,w0.w,a0[3]);  a1[3]=fmaf(x.y,w0.w,a1[3]);
      a0[4]=fmaf(x.x,w1.x,a0[4]);  a1[4]=fmaf(x.y,w1.x,a1[4]);
      a0[5]=fmaf(x.x,w1.y,a0[5]);  a1[5]=fmaf(x.y,w1.y,a1[5]);
      a0[6]=fmaf(x.x,w1.z,a0[6]);  a1[6]=fmaf(x.y,w1.z,a1[6]);
      a0[7]=fmaf(x.x,w1.w,a0[7]);  a1[7]=fmaf(x.y,w1.w,a1[7]);
      a0[8]=fmaf(x.x,w2.x,a0[8]);  a1[8]=fmaf(x.y,w2.x,a1[8]);
      a0[9]=fmaf(x.x,w2.y,a0[9]);  a1[9]=fmaf(x.y,w2.y,a1[9]);
      a0[10]=fmaf(x.x,w2.z,a0[10]); a1[10]=fmaf(x.y,w2.z,a1[10]);
      a0[11]=fmaf(x.x,w2.w,a0[11]); a1[11]=fmaf(x.y,w2.w,a1[11]);
      a0[12]=fmaf(x.x,w3.x,a0[12]); a1[12]=fmaf(x.y,w3.x,a1[12]);
      a0[13]=fmaf(x.x,w3.y,a0[13]); a1[13]=fmaf(x.y,w3.y,a1[13]);
      a0[14]=fmaf(x.x,w3.z,a0[14]); a1[14]=fmaf(x.y,w3.z,a1[14]);
      a0[15]=fmaf(x.x,w3.w,a0[15]); a1[15]=fmaf(x.y,w3.w,a1[15]);
    }
    float4* q0 = (float4*)(wf + OFF_Q + (size_t)n*131072 + (size_t)t0*16);
    q0[0] = make_float4(a0[0],a0[1],a0[2],a0[3]);
    q0[1] = make_float4(a0[4],a0[5],a0[6],a0[7]);
    q0[2] = make_float4(a0[8],a0[9],a0[10],a0[11]);
    q0[3] = make_float4(a0[12],a0[13],a0[14],a0[15]);
    q0[4] = make_float4(a1[0],a1[1],a1[2],a1[3]);
    q0[5] = make_float4(a1[4],a1[5],a1[6],a1[7]);
    q0[6] = make_float4(a1[8],a1[9],a1[10],a1[11]);
    q0[7] = make_float4(a1[12],a1[13],a1[14],a1[15]);
    wf[OFF_XX + (size_t)n*T_TOT + t0]     = s20;
    wf[OFF_XX + (size_t)n*T_TOT + t0 + 1] = s21;
    return;
  }

  // ---------------- block 0: setup in LDS (256 thr) ----------------
  __shared__ float Wl[VD][16];
  __shared__ float Al[16][16], Sm_l[16][16], Qm_l[16][16], S0_l[16][16];
  const int ri = tid >> 4, ci = tid & 15;
  for (int e = tid; e < VD*16; e += 256) Wl[e>>4][e&15] = W[e];
  Al[ri][ci] = A[tid];
  __syncthreads();
  {
    float s = 0.f;
    for (int r = 0; r < VD; ++r) s = fmaf(Wl[r][ri], Wl[r][ci], s);
    Sm_l[ri][ci] = s;
    int m = ri < ci ? ri : ci;
    float q = (ri==ci)?1e-6f:0.f, g0 = (ri==ci)?1e-6f:0.f;
    for (int r = 0; r <= m; ++r) {
      q  = fmaf(B[ri*16+r],   B[ci*16+r],   q);
      g0 = fmaf(S0h[ri*16+r], S0h[ci*16+r], g0);
    }
    Qm_l[ri][ci] = q;
    S0_l[ri][ci] = g0;
  }
  __syncthreads();
  if (tid >= 64) return;

  // ---------------- wave 0: register Riccati ----------------
  const int lane = tid;
  const int i = lane >> 2, g = lane & 3;
  const int bA = 4*g, bT = 64*g;
  float al[4], sm[4], qm[4], s0[4], scl[4], scl0[4], dmask[4];
  {
    float4 t;
    t = *(const float4*)&Al[i][4*g];   al[0]=t.x; al[1]=t.y; al[2]=t.z; al[3]=t.w;
    t = *(const float4*)&Sm_l[i][4*g]; sm[0]=t.x; sm[1]=t.y; sm[2]=t.z; sm[3]=t.w;
    t = *(const float4*)&Qm_l[i][4*g]; qm[0]=t.x; qm[1]=t.y; qm[2]=t.z; qm[3]=t.w;
    t = *(const float4*)&S0_l[i][4*g]; s0[0]=t.x; s0[1]=t.y; s0[2]=t.z; s0[3]=t.w;
  }
  #pragma unroll
  for (int j = 0; j < 4; ++j) dmask[j] = (4*g + j == i) ? 1.f : 0.f;

  float ev = expf(lsv[0]); float var = ev*ev;
  float c0v = var + 1e-6f, cv = var + 2e-6f;
  float invc0 = 1.f/c0v, invc = 1.f/cv;
  float logc = __logf(cv);
  #pragma unroll
  for (int j = 0; j < 4; ++j) { scl0[j] = sm[j]*invc0; scl[j] = sm[j]*invc; }

  // t=0: G0 = I + Sigma0*(S/c0); P0 = G0^-1 Sigma0
  float gm[4];
  mmF(gm, s0, scl0, bA);
  #pragma unroll
  for (int j = 0; j < 4; ++j) gm[j] += dmask[j];
  double dp0 = 1.0;
  gjF(gm, s0, bA, i, dp0);                   // s0 := P0
  float ldet_first = 0.5f*(64.f*__logf(c0v) + __logf((float)dp0));
  {
    float4* w4;
    w4 = (float4*)(wf + OFF_P0 + i*16 + 4*g); *w4 = make_float4(s0[0],s0[1],s0[2],s0[3]);
    w4 = (float4*)(wf + OFF_S  + i*16 + 4*g); *w4 = make_float4(sm[0],sm[1],sm[2],sm[3]);
  }

  float p[4];
  #pragma unroll
  for (int j = 0; j < 4; ++j) p[j] = s0[j];

  double dacc = 0.0; float ld_t = 0.f;
  float t1[4], sd[4];
  #pragma unroll 1
  for (int t = 0; t < NI; ++t) {
    mmF(t1, al, p, bA);                      // A P
    mmbtF(sd, t1, al, bT);                   // A P A^T
    #pragma unroll
    for (int j = 0; j < 4; ++j) sd[j] += qm[j];        // Sd
    mmF(gm, sd, scl, bA);                    // Sd S/c
    #pragma unroll
    for (int j = 0; j < 4; ++j) gm[j] += dmask[j];     // G
    double dp = 1.0;
    gjF(gm, sd, bA, i, dp);                  // sd := P_new
    #pragma unroll
    for (int j = 0; j < 4; ++j) p[j] = sd[j];
    ld_t = 0.5f*(64.f*logc + __logf((float)dp));
    dacc += (double)ld_t;
  }
  double ldet_total = dacc + (double)(T_TOT-1-NI)*(double)ld_t;

  // steady state: Kq = A P/c ; F = A - Kq S ; M16 = F^16
  float kq[4], fm_[4], tB[4];
  mmF(t1, al, p, bA);
  #pragma unroll
  for (int j = 0; j < 4; ++j) kq[j] = t1[j]*invc;
  mmF(tB, kq, sm, bA);
  #pragma unroll
  for (int j = 0; j < 4; ++j) fm_[j] = al[j] - tB[j];
  {
    float4* w4;
    w4 = (float4*)(wf + OFF_PSS + i*16 + 4*g); *w4 = make_float4(p[0],p[1],p[2],p[3]);
    w4 = (float4*)(wf + OFF_F   + i*16 + 4*g); *w4 = make_float4(fm_[0],fm_[1],fm_[2],fm_[3]);
    w4 = (float4*)(wf + OFF_KQ  + i*16 + 4*g); *w4 = make_float4(kq[0],kq[1],kq[2],kq[3]);
  }
  mmF(t1, fm_, fm_, bA);   // F^2
  mmF(tB, t1, t1, bA);     // F^4
  mmF(t1, tB, tB, bA);     // F^8
  mmF(tB, t1, t1, bA);     // F^16
  {
    float4* w4 = (float4*)(wf + OFF_M16 + i*16 + 4*g);
    *w4 = make_float4(tB[0],tB[1],tB[2],tB[3]);
  }
  if (lane == 0) {
    double* d = (double*)wf;
    d[0] = (double)ldet_first;
    d[1] = ldet_total;
    wf[OFF_FS+0] = c0v; wf[OFF_FS+1] = cv; wf[OFF_FS+2] = invc; wf[OFF_FS+3] = invc0;
  }
}

// =====================================================================
// Pass A: chunk-local offsets (F-form) + t0-term block (x == NCHUNK).
// =====================================================================
__global__ __launch_bounds__(256) void k_passA(const float* __restrict__ A,
                                               const float* __restrict__ mu0)
{
  const int tid = threadIdx.x; const int j = tid & 15;
  const int n = blockIdx.y*16 + (tid >> 4);
  float* __restrict__ wf = g_wf;

  if (blockIdx.x == NCHUNK) {
    float Ar[16], Sr[16], P0r[16];
    #pragma unroll
    for (int k = 0; k < 16; ++k) {
      Ar[k]  = A[j*16+k];
      Sr[k]  = wf[OFF_S  + j*16 + k];
      P0r[k] = wf[OFF_P0 + j*16 + k];
    }
    const float invc0 = wf[OFF_FS+3];
    float mu0j = mu0[j];
    float q0  = wf[OFF_Q + (size_t)n*131072 + j];
    float xx0 = wf[OFF_XX + (size_t)n*T_TOT];
    float h0; MV16(Sr, mu0j, h0);
    float u0 = q0 - h0;
    float w0; MV16(P0r, u0, w0);
    float loc = fmaf(-2.f*q0, mu0j, fmaf(mu0j, h0, -(u0*w0*invc0)));
    RED16(loc);
    if (j == 0) wf[OFF_FQ + n] = (xx0 + loc)*invc0;
    float muf = fmaf(w0, invc0, mu0j);
    float en; MV16(Ar, muf, en);
    wf[OFF_EN0 + n*16 + j] = en;
    return;
  }

  const int chunk = blockIdx.x;
  float Fr[16], Kr[16];
  #pragma unroll
  for (int k = 0; k < 16; ++k) {
    Fr[k] = wf[OFF_F  + j*16 + k];
    Kr[k] = wf[OFF_KQ + j*16 + k];
  }
  const int t0 = 1 + CHLEN*chunk;
  const float* qp = wf + OFF_Q + (size_t)n*131072 + (size_t)t0*16 + j;
  float mud = 0.f;
  #pragma unroll
  for (int s = 0; s < CHLEN; ++s) {
    float qj = qp[s*16];
    float g; MV16(Kr, qj, g);
    float fm; MV16(Fr, mud, fm);
    mud = fm + g;
  }
  wf[OFF_VC + chunk*512 + n*16 + j] = mud;
}

// =====================================================================
// Pass C: parallel entry reconstruction + F-form replay + LL quadratics.
// =====================================================================
__global__ __launch_bounds__(256) void k_passC()
{
  const int tid = threadIdx.x; const int j = tid & 15;
  const int n = blockIdx.y*16 + (tid >> 4);
  const int chunk = blockIdx.x;
  float* __restrict__ wf = g_wf;
  float Fr[16], Kr[16], Sr[16], Pr[16];
  #pragma unroll
  for (int k = 0; k < 16; ++k) {
    Fr[k] = wf[OFF_F   + j*16 + k];
    Kr[k] = wf[OFF_KQ  + j*16 + k];
    Sr[k] = wf[OFF_S   + j*16 + k];
    Pr[k] = wf[OFF_PSS + j*16 + k];
  }
  const float invc = wf[OFF_FS+2];

  float mud;
  if (chunk == 0) {
    mud = wf[OFF_EN0 + n*16 + j];
  } else {
    float Mr[16];
    #pragma unroll
    for (int k = 0; k < 16; ++k) Mr[k] = wf[OFF_M16 + j*16 + k];
    float v1 = wf[OFF_VC + (chunk-1)*512 + n*16 + j];
    float x2 = (chunk == 1) ? wf[OFF_EN0 + n*16 + j]
                            : wf[OFF_VC + (chunk-2)*512 + n*16 + j];
    float x3 = (chunk == 2) ? wf[OFF_EN0 + n*16 + j]
             : (chunk >= 3) ? wf[OFF_VC + (chunk-3)*512 + n*16 + j] : 0.f;
    float m3; MV16(Mr, x3, m3);
    float y = x2 + m3;
    float m2; MV16(Mr, y, m2);
    mud = v1 + m2;
  }

  const int t0 = 1 + CHLEN*chunk;
  const int ns = (CHLEN < (T_TOT-1) - t0 + 1) ? CHLEN : ((T_TOT-1) - t0 + 1);
  const float* qp  = wf + OFF_Q  + (size_t)n*131072 + (size_t)t0*16 + j;
  const float* xxp = wf + OFF_XX + (size_t)n*T_TOT + t0;
  float qacc = 0.f;
  #pragma unroll
  for (int s = 0; s < CHLEN; ++s) {
    float qj = qp[s*16];
    float xxv = xxp[s];
    // quadratic (off the state chain)
    float h; MV16(Sr, mud, h);
    float u = qj - h;
    float w; MV16(Pr, u, w);
    float loc = fmaf(-2.f*qj, mud, fmaf(mud, h, -(u*w*invc)));
    RED16(loc);
    if (s < ns) qacc = fmaf(xxv + loc, invc, qacc);
    // state chain: mud' = F*mud + Kq*q (1 matvec deep)
    float gq; MV16(Kr, qj, gq);
    float fm; MV16(Fr, mud, fm);
    mud = fm + gq;
  }
  if (j == 0) wf[OFF_QS + chunk*32 + n] = qacc;
}

// =====================================================================
// Final assembly: 8 slices x 32 trials, LDS reduce.
// =====================================================================
__global__ __launch_bounds__(256) void k_final(float* __restrict__ out)
{
  const int tid = threadIdx.x;
  const int slice = tid >> 5, n = tid & 31;
  const float* wf = g_wf;
  __shared__ double red[8][32];
  double acc = 0.0;
  #pragma unroll 8
  for (int k = 0; k < NCHUNK/8; ++k)
    acc += (double)wf[OFF_QS + (slice*(NCHUNK/8) + k)*32 + n];
  red[slice][n] = acc;
  __syncthreads();
  if (tid < 32) {
    const double* dsc = (const double*)wf;
    double a = (double)wf[OFF_FQ + tid];
    #pragma unroll
    for (int s = 0; s < 8; ++s) a += red[s][tid];
    const double LOG2PI = 1.8378770664093453;
    double ll = -32.0*LOG2PI*(double)T_TOT - dsc[0] - dsc[1] - 0.5*a;
    out[tid] = (float)ll;
  }
}

extern "C" void kernel_launch(void* const* d_in, const int* in_sizes, int n_in,
                              void* d_out, int out_size, void* d_ws, size_t ws_size,
                              hipStream_t stream)
{
  (void)in_sizes; (void)n_in; (void)out_size; (void)d_ws; (void)ws_size;
  const float* v   = (const float*)d_in[0];
  const float* A   = (const float*)d_in[1];
  const float* B   = (const float*)d_in[2];
  const float* W   = (const float*)d_in[3];
  const float* mu0 = (const float*)d_in[4];
  const float* S0h = (const float*)d_in[5];
  const float* lsv = (const float*)d_in[6];
  float* out = (float*)d_out;

  k_front<<<1 + NTR*16, 256, 0, stream>>>(v, A, B, W, S0h, lsv);
  k_passA<<<dim3(NCHUNK+1,2), 256, 0, stream>>>(A, mu0);
  k_passC<<<dim3(NCHUNK,2), 256, 0, stream>>>();
  k_final<<<1, 256, 0, stream>>>(out);
}